// Round 5
// baseline (600.505 us; speedup 1.0000x reference)
//
#include <hip/hip_runtime.h>
#include <hip/hip_bf16.h>

#define DIMD 2048
#define NHD 16
#define QLORA 1536
#define KVLORA 512
#define QKD 192
#define BBD 2
#define SSD 2048
#define BSD (BBD*SSD)       // 4096 tokens
#define KVPAD 640           // 576 padded to multiple of 128
#define BHN (BBD*NHD)       // 32 (b,h) pairs
#define EPSF 1.1920929e-07f
#define SCALEF 0.07216878364870322f  // 192^-0.5 (folded into Q at build_q)

typedef __hip_bfloat16 bf16;
typedef __attribute__((ext_vector_type(8))) short short8;
typedef __attribute__((ext_vector_type(4))) float floatx4;

typedef __attribute__((address_space(1))) char as1_char;
typedef __attribute__((address_space(3))) char as3_char;
#define GLD16(g, l) __builtin_amdgcn_global_load_lds((as1_char*)(g), (as3_char*)(l), 16, 0, 0)

// ---------------- block reduction (256 threads = 4 waves) ----------------
__device__ __forceinline__ float block_sum(float x) {
#pragma unroll
  for (int o = 32; o > 0; o >>= 1) x += __shfl_xor(x, o, 64);
  __shared__ float red[4];
  __syncthreads();
  if ((threadIdx.x & 63) == 0) red[threadIdx.x >> 6] = x;
  __syncthreads();
  return red[0] + red[1] + red[2] + red[3];
}

// ---------------- generic bf16 MFMA GEMM (128x128 tile):  C = A*B^T + bias ----------------
// Kept for shapes not divisible by 256 (Wkv_down N=640). XCD bijective swizzle.
template<bool STORE_BF16>
__global__ __launch_bounds__(256)
void gemm_bt(const bf16* __restrict__ A, const bf16* __restrict__ Bm,
             const float* __restrict__ bias, void* __restrict__ Cp,
             int M, int N, int K, long sA, long sB, long sC, int ldc)
{
  int nwg = gridDim.x * gridDim.y;
  int lin = blockIdx.y * gridDim.x + blockIdx.x;
  int xcd = lin & 7, l8 = lin >> 3;
  int qd = nwg >> 3, rd = nwg & 7;
  int wg = (xcd < rd ? xcd * (qd + 1) : rd * (qd + 1) + (xcd - rd) * qd) + l8;
  int bx = wg % gridDim.x, by = wg / gridDim.x;

  int m0 = by * 128, n0 = bx * 128;
  long z = blockIdx.z;
  A  += z * sA;
  Bm += z * sB;

  __shared__ __align__(16) bf16 Asm[128 * 32];
  __shared__ __align__(16) bf16 Bsm[128 * 32];

  const int tid  = threadIdx.x;
  const int lane = tid & 63;
  const int wv   = tid >> 6;
  const int wm   = (wv >> 1) << 6;
  const int wn   = (wv & 1) << 6;
  const int fr   = lane & 15;
  const int q8   = (lane >> 4) << 3;

  floatx4 acc[4][4];
#pragma unroll
  for (int i = 0; i < 4; ++i)
#pragma unroll
    for (int j = 0; j < 4; ++j)
      acc[i][j] = (floatx4){0.f, 0.f, 0.f, 0.f};

  for (int k0 = 0; k0 < K; k0 += 32) {
    __syncthreads();
#pragma unroll
    for (int it = 0; it < 2; ++it) {
      int seg = it * 256 + tid;
      int row = seg >> 2, cs = seg & 3;
      GLD16(A  + (long)(m0 + row) * K + k0 + cs * 8, &Asm[(it * 256 + wv * 64) * 8]);
      GLD16(Bm + (long)(n0 + row) * K + k0 + cs * 8, &Bsm[(it * 256 + wv * 64) * 8]);
    }
    __syncthreads();

    short8 fa[4], fb[4];
#pragma unroll
    for (int t = 0; t < 4; ++t) fa[t] = *(const short8*)&Asm[(wm + t * 16 + fr) * 32 + q8];
#pragma unroll
    for (int t = 0; t < 4; ++t) fb[t] = *(const short8*)&Bsm[(wn + t * 16 + fr) * 32 + q8];
#pragma unroll
    for (int i = 0; i < 4; ++i)
#pragma unroll
      for (int j = 0; j < 4; ++j)
        acc[i][j] = __builtin_amdgcn_mfma_f32_16x16x32_bf16(fa[i], fb[j], acc[i][j], 0, 0, 0);
  }

  long cb = z * sC;
  int rq = (lane >> 4) * 4;
#pragma unroll
  for (int i = 0; i < 4; ++i) {
#pragma unroll
    for (int j = 0; j < 4; ++j) {
      int col = n0 + wn + j * 16 + fr;
      float bv = bias ? bias[col] : 0.f;
#pragma unroll
      for (int r = 0; r < 4; ++r) {
        int rowg = m0 + wm + i * 16 + rq + r;
        float v = acc[i][j][r] + bv;
        if (STORE_BF16)
          ((bf16*)Cp)[cb + (long)rowg * ldc + col] = __float2bfloat16(v);
        else
          ((float*)Cp)[cb + (long)rowg * ldc + col] = v;
      }
    }
  }
}

// ---------------- big-tile bf16 MFMA GEMM (256x256, BK=64, counted-vmcnt pipeline) ----------------
// 512 threads = 8 waves (2M x 4N), per-wave C = 128x64 (acc[8][4]); 64 MFMA/wave
// per K-tile between one barrier pair. K/V-style chunked LDS [chunk][256r][32c]
// with seg-XOR ((r>>1)&3) swizzle, both-sides (pre-swizzled global source for
// global_load_lds + swizzled ds_read). Double-buffered; counted vmcnt(8) lets the
// next tile's 8 loads stay in flight across the raw s_barrier (T4); setprio(1)
// around the MFMA cluster (T5). LDS=128KB -> 1 block/CU, 2 waves/SIMD.
// Requires M,N multiples of 256 and K multiple of 64.
template<bool STORE_BF16>
__global__ __launch_bounds__(512, 2)
void gemm_bt2(const bf16* __restrict__ A, const bf16* __restrict__ Bm,
              const float* __restrict__ bias, void* __restrict__ Cp, int K, int ldc)
{
  int nwg = gridDim.x * gridDim.y;
  int lin = blockIdx.y * gridDim.x + blockIdx.x;
  int xcd = lin & 7, l8 = lin >> 3;
  int qd = nwg >> 3, rd = nwg & 7;
  int wg = (xcd < rd ? xcd * (qd + 1) : rd * (qd + 1) + (xcd - rd) * qd) + l8;
  int bx = wg % gridDim.x, by = wg / gridDim.x;
  int m0 = by * 256, n0 = bx * 256;

  __shared__ __align__(16) bf16 SA[2][16384];  // [buf][chunk*8192 + r*32 + seg*8] 64KB
  __shared__ __align__(16) bf16 SB[2][16384];  // 64KB

  const int tid  = threadIdx.x;
  const int lane = tid & 63;
  const int wv   = tid >> 6;       // 0..7
  const int wm   = (wv >> 2) << 7; // 0 or 128
  const int wn   = (wv & 3) << 6;  // 0,64,128,192
  const int fr   = lane & 15;
  const int g4   = lane >> 4;

  // staging tables: per chunk, 2 iterations cover 256 rows x 4 segs (seg pre-swizzled)
  int sr[2], ss[2];
#pragma unroll
  for (int it = 0; it < 2; ++it) {
    int seg = it * 512 + tid;
    int r = seg >> 2, s4 = seg & 3;
    sr[it] = r;
    ss[it] = s4 ^ ((r >> 1) & 3);
  }
  // fragment read offsets (row*32 + swizzled 8-elem seg)
  int asw[8], bsw[4];
#pragma unroll
  for (int i = 0; i < 8; ++i) {
    int row = wm + i * 16 + fr;
    asw[i] = row * 32 + (((g4 ^ (row >> 1)) & 3) << 3);
  }
#pragma unroll
  for (int j = 0; j < 4; ++j) {
    int row = wn + j * 16 + fr;
    bsw[j] = row * 32 + (((g4 ^ (row >> 1)) & 3) << 3);
  }

  floatx4 acc[8][4];
#pragma unroll
  for (int i = 0; i < 8; ++i)
#pragma unroll
    for (int j = 0; j < 4; ++j)
      acc[i][j] = (floatx4){0.f, 0.f, 0.f, 0.f};

  const bf16* Ab = A + (long)m0 * K;
  const bf16* Bb = Bm + (long)n0 * K;

  auto stage = [&](int t, int buf) {
    const long k0 = (long)t << 6;
#pragma unroll
    for (int c = 0; c < 2; ++c)
#pragma unroll
      for (int it = 0; it < 2; ++it)
        GLD16(Ab + (long)sr[it] * K + k0 + c * 32 + ss[it] * 8,
              &SA[buf][c * 8192 + (it * 512 + tid) * 8]);
#pragma unroll
    for (int c = 0; c < 2; ++c)
#pragma unroll
      for (int it = 0; it < 2; ++it)
        GLD16(Bb + (long)sr[it] * K + k0 + c * 32 + ss[it] * 8,
              &SB[buf][c * 8192 + (it * 512 + tid) * 8]);
  };

  const int nt = K >> 6;
  stage(0, 0);

#pragma unroll 1
  for (int t = 0; t < nt; ++t) {
    if (t + 1 < nt) {
      stage(t + 1, (t + 1) & 1);
      asm volatile("s_waitcnt vmcnt(8)" ::: "memory");  // tile t's 8 loads landed
    } else {
      asm volatile("s_waitcnt vmcnt(0)" ::: "memory");
    }
    __builtin_amdgcn_sched_barrier(0);
    __builtin_amdgcn_s_barrier();
    __builtin_amdgcn_sched_barrier(0);

    const bf16* abuf = SA[t & 1];
    const bf16* bbuf = SB[t & 1];
#pragma unroll
    for (int ks = 0; ks < 2; ++ks) {
      short8 af[8], bfr[4];
#pragma unroll
      for (int i = 0; i < 8; ++i) af[i] = *(const short8*)(abuf + ks * 8192 + asw[i]);
#pragma unroll
      for (int j = 0; j < 4; ++j) bfr[j] = *(const short8*)(bbuf + ks * 8192 + bsw[j]);
      __builtin_amdgcn_s_setprio(1);
#pragma unroll
      for (int i = 0; i < 8; ++i)
#pragma unroll
        for (int j = 0; j < 4; ++j)
          acc[i][j] = __builtin_amdgcn_mfma_f32_16x16x32_bf16(af[i], bfr[j], acc[i][j], 0, 0, 0);
      __builtin_amdgcn_s_setprio(0);
    }

    __builtin_amdgcn_sched_barrier(0);
    __builtin_amdgcn_s_barrier();
    __builtin_amdgcn_sched_barrier(0);
  }

  // ---- epilogue: bias + store ----
  int rq = g4 * 4;
#pragma unroll
  for (int i = 0; i < 8; ++i) {
#pragma unroll
    for (int j = 0; j < 4; ++j) {
      int col = n0 + wn + j * 16 + fr;
      float bv = bias ? bias[col] : 0.f;
#pragma unroll
      for (int r = 0; r < 4; ++r) {
        int rowg = m0 + wm + i * 16 + rq + r;
        float v = acc[i][j][r] + bv;
        if (STORE_BF16)
          ((bf16*)Cp)[(long)rowg * ldc + col] = __float2bfloat16(v);
        else
          ((float*)Cp)[(long)rowg * ldc + col] = v;
      }
    }
  }
}

// ---------------- fused flash attention (causal), two tiles per block ----------------
// (unchanged from R4 -- best verified flash structure)
__global__ __launch_bounds__(512, 2)
void flash_attn(const bf16* __restrict__ Qh, const bf16* __restrict__ Kh,
                const bf16* __restrict__ Vt, bf16* __restrict__ attnall)
{
  const int lin = blockIdx.x;
  const int bh  = lin & 31;
  const int p   = lin >> 5;            // 0..7
  const int qtA = 15 - p;
  const int b = bh >> 4, h = bh & 15;

  const bf16* Qg = Qh + (long)bh * SSD * QKD;
  const bf16* Kg = Kh + (long)bh * SSD * QKD;
  const bf16* Vg = Vt + (long)bh * 128 * SSD;

  __shared__ __align__(16) bf16 SM[57344];
  bf16* KB0 = SM;
  bf16* KB1 = SM + 12288;
  bf16* VB0 = SM + 24576;
  bf16* VB1 = SM + 32768;
  bf16* PB  = SM + 40960;

  const int tid  = threadIdx.x;
  const int lane = tid & 63;
  const int wv   = tid >> 6;       // 0..7
  const int w4   = wv & 3;
  const int tb   = wv >> 2;        // 0 = tile A, 1 = tile B
  const int fr   = lane & 15;
  const int g4   = lane >> 4;

  const int qt    = tb ? (p) : (qtA);
  const int qbase = qt << 7;
  const int jmax  = 2 * qtA + 1;

  long kofs[3]; int kdst[3];
#pragma unroll
  for (int it = 0; it < 3; ++it) {
    int seg = it * 512 + tid;
    int c = seg >> 8, rs = seg & 255;
    int r = rs >> 2, s = (rs & 3) ^ ((r >> 1) & 3);
    kofs[it] = (long)r * QKD + c * 32 + s * 8;
    kdst[it] = c * 2048 + rs * 8;
  }
  long vofs[2]; int vdst[2];
#pragma unroll
  for (int it = 0; it < 2; ++it) {
    int seg = it * 512 + tid;
    int c2 = seg >> 9, ds = seg & 511;
    int d = ds >> 2, s = (ds & 3) ^ ((d >> 1) & 3);
    vofs[it] = (long)d * SSD + c2 * 32 + s * 8;
    vdst[it] = c2 * 4096 + ds * 8;
  }
  int fsw[4];
#pragma unroll
  for (int n = 0; n < 4; ++n) {
    int row = n * 16 + fr;
    fsw[n] = row * 32 + (((g4 ^ (row >> 1)) & 3) << 3);
  }
  int vsw[8];
#pragma unroll
  for (int dn = 0; dn < 8; ++dn) {
    int row = dn * 16 + fr;
    vsw[dn] = row * 32 + (((g4 ^ (row >> 1)) & 3) << 3);
  }
  int qoff[2];
#pragma unroll
  for (int i = 0; i < 2; ++i) {
    int row = wv * 32 + i * 16 + fr;
    qoff[i] = row * 32 + (((g4 ^ (row >> 1)) & 3) << 3);
  }

  const int qbA = qtA << 7, qbB = p << 7;
#pragma unroll
  for (int it = 0; it < 12; ++it) {
    int seg = it * 512 + tid;
    int c = seg >> 10, rs = seg & 1023;
    int r = rs >> 2, s = (rs & 3) ^ ((r >> 1) & 3);
    int grow = (r < 128) ? (qbA + r) : (qbB + r - 128);
    GLD16(Qg + (long)grow * QKD + c * 32 + s * 8, SM + c * 8192 + rs * 8);
  }
  __syncthreads();
  short8 qf[2][6];
#pragma unroll
  for (int i = 0; i < 2; ++i)
#pragma unroll
    for (int c = 0; c < 6; ++c)
      qf[i][c] = *(const short8*)(SM + c * 8192 + qoff[i]);

  floatx4 oacc[2][8];
#pragma unroll
  for (int i = 0; i < 2; ++i)
#pragma unroll
    for (int n = 0; n < 8; ++n) oacc[i][n] = (floatx4){0.f, 0.f, 0.f, 0.f};
  float mi[2][4], li[2][4];
#pragma unroll
  for (int i = 0; i < 2; ++i)
#pragma unroll
    for (int r = 0; r < 4; ++r) { mi[i][r] = -1e30f; li[i][r] = 0.f; }

  __syncthreads();

  auto stageKV = [&](int jb2, bf16* kb2, bf16* vb2) {
#pragma unroll
    for (int it = 0; it < 3; ++it)
      GLD16(Kg + (long)jb2 * QKD + kofs[it], kb2 + kdst[it]);
#pragma unroll
    for (int it = 0; it < 2; ++it)
      GLD16(Vg + jb2 + vofs[it], vb2 + vdst[it]);
  };

  stageKV(0, KB0, VB0);

#pragma unroll 1
  for (int j = 0; j <= jmax; ++j) {
    const int jb = j << 6;
    if (j < jmax) {
      stageKV((j + 1) << 6, (j & 1) ? KB0 : KB1, (j & 1) ? VB0 : VB1);
      asm volatile("s_waitcnt vmcnt(5)" ::: "memory");
    } else {
      asm volatile("s_waitcnt vmcnt(0)" ::: "memory");
    }
    __builtin_amdgcn_sched_barrier(0);
    __builtin_amdgcn_s_barrier();
    __builtin_amdgcn_sched_barrier(0);

    const bf16* kb = (j & 1) ? KB1 : KB0;
    const bf16* vb = (j & 1) ? VB1 : VB0;
    const bool active = (jb <= qbase + w4 * 32 + 31);
    if (active) {
      floatx4 sacc[2][4];
#pragma unroll
      for (int i = 0; i < 2; ++i)
#pragma unroll
        for (int n = 0; n < 4; ++n) sacc[i][n] = (floatx4){0.f, 0.f, 0.f, 0.f};
      __builtin_amdgcn_s_setprio(1);
#pragma unroll
      for (int c = 0; c < 6; ++c) {
#pragma unroll
        for (int n = 0; n < 4; ++n) {
          short8 fb = *(const short8*)(kb + c * 2048 + fsw[n]);
#pragma unroll
          for (int i = 0; i < 2; ++i)
            sacc[i][n] = __builtin_amdgcn_mfma_f32_16x16x32_bf16(qf[i][c], fb, sacc[i][n], 0, 0, 0);
        }
      }
      __builtin_amdgcn_s_setprio(0);

      float pm[2][4];
#pragma unroll
      for (int i = 0; i < 2; ++i) {
        const int rbase = qbase + w4 * 32 + i * 16;
        const bool diag = (jb + 63 > rbase);
#pragma unroll
        for (int r = 0; r < 4; ++r) {
          if (diag) {
            int rowg = rbase + g4 * 4 + r;
#pragma unroll
            for (int n = 0; n < 4; ++n)
              if ((jb + n * 16 + fr) > rowg) sacc[i][n][r] = -1e30f;
          }
          pm[i][r] = fmaxf(fmaxf(sacc[i][0][r], sacc[i][1][r]),
                           fmaxf(sacc[i][2][r], sacc[i][3][r]));
        }
      }
      int nn = 0;
#pragma unroll
      for (int i = 0; i < 2; ++i)
#pragma unroll
        for (int r = 0; r < 4; ++r) nn |= (pm[i][r] > mi[i][r]);
      if (__any(nn)) {
#pragma unroll
        for (int i = 0; i < 2; ++i) {
#pragma unroll
          for (int r = 0; r < 4; ++r) {
            float mx = pm[i][r];
#pragma unroll
            for (int off = 1; off < 16; off <<= 1) mx = fmaxf(mx, __shfl_xor(mx, off, 64));
            float mnew = fmaxf(mi[i][r], mx);
            float alpha = __expf(mi[i][r] - mnew);
            mi[i][r] = mnew;
            li[i][r] *= alpha;
#pragma unroll
            for (int n = 0; n < 8; ++n) oacc[i][n][r] *= alpha;
          }
        }
      }
#pragma unroll
      for (int i = 0; i < 2; ++i) {
#pragma unroll
        for (int r = 0; r < 4; ++r) {
          float acc = 0.f;
#pragma unroll
          for (int n = 0; n < 4; ++n) {
            float pv = __expf(sacc[i][n][r] - mi[i][r]);
            sacc[i][n][r] = pv;
            acc += pv;
          }
          li[i][r] += acc;
        }
      }

#pragma unroll
      for (int i = 0; i < 2; ++i) {
#pragma unroll
        for (int n = 0; n < 4; ++n) {
          int c2 = n >> 1;
          int col = (n & 1) * 16 + fr;
#pragma unroll
          for (int r = 0; r < 4; ++r) {
            int m = wv * 32 + i * 16 + g4 * 4 + r;
            int cw = (((col >> 3) ^ ((m >> 1) & 3)) << 3) | (col & 7);
            PB[c2 * 8192 + m * 32 + cw] = __float2bfloat16(sacc[i][n][r]);
          }
        }
      }

      __builtin_amdgcn_s_setprio(1);
#pragma unroll
      for (int c2 = 0; c2 < 2; ++c2) {
        short8 pf[2];
#pragma unroll
        for (int i = 0; i < 2; ++i)
          pf[i] = *(const short8*)(PB + c2 * 8192 + qoff[i]);
#pragma unroll
        for (int dn = 0; dn < 8; ++dn) {
          short8 vf = *(const short8*)(vb + c2 * 4096 + vsw[dn]);
#pragma unroll
          for (int i = 0; i < 2; ++i)
            oacc[i][dn] = __builtin_amdgcn_mfma_f32_16x16x32_bf16(pf[i], vf, oacc[i][dn], 0, 0, 0);
        }
      }
      __builtin_amdgcn_s_setprio(0);
    }

    __builtin_amdgcn_sched_barrier(0);
    __builtin_amdgcn_s_barrier();
    __builtin_amdgcn_sched_barrier(0);
  }

#pragma unroll
  for (int i = 0; i < 2; ++i) {
#pragma unroll
    for (int r = 0; r < 4; ++r) {
      float l = li[i][r];
#pragma unroll
      for (int off = 1; off < 16; off <<= 1) l += __shfl_xor(l, off, 64);
      float inv = 1.f / l;
      int m = qbase + w4 * 32 + i * 16 + g4 * 4 + r;
      bf16* orow = attnall + ((long)(b * SSD + m) * NHD + h) * 128;
#pragma unroll
      for (int dn = 0; dn < 8; ++dn)
        orow[dn * 16 + fr] = __float2bfloat16(oacc[i][dn][r] * inv);
    }
  }
}

// ---------------- fused fp32 -> bf16 converts (float4-vectorized) ----------------
__device__ __forceinline__ void cvt4(const float* __restrict__ s, bf16* __restrict__ d,
                                     long se, long de) {
  float4 v = *(const float4*)(s + se);
  union { bf16 h[4]; uint2 u; } o;
  o.h[0] = __float2bfloat16(v.x); o.h[1] = __float2bfloat16(v.y);
  o.h[2] = __float2bfloat16(v.z); o.h[3] = __float2bfloat16(v.w);
  *(uint2*)(d + de) = o.u;
}

#define NX4   ((long)BSD * DIMD / 4)
#define NQD4  ((long)QLORA * DIMD / 4)
#define NQU4  ((long)3072 * QLORA / 4)
#define NKVD4 ((long)KVPAD * DIMD / 4)
#define NKVU4 ((long)4096 * KVLORA / 4)
#define NWO4  ((long)DIMD * 2048 / 4)

__global__ __launch_bounds__(256)
void cvt_all(const float* __restrict__ x, const float* __restrict__ wqd,
             const float* __restrict__ wqu, const float* __restrict__ wkvd,
             const float* __restrict__ wkvu, const float* __restrict__ wo,
             bf16* __restrict__ dx, bf16* __restrict__ dwqd, bf16* __restrict__ dwqu,
             bf16* __restrict__ dwkvd, bf16* __restrict__ dwkvu, bf16* __restrict__ dwo)
{
  long i = (long)blockIdx.x * 256 + threadIdx.x;
  if (i < NX4) { cvt4(x, dx, i * 4, i * 4); return; }
  i -= NX4;
  if (i < NQD4) { cvt4(wqd, dwqd, i * 4, i * 4); return; }
  i -= NQD4;
  if (i < NQU4) { cvt4(wqu, dwqu, i * 4, i * 4); return; }
  i -= NQU4;
  if (i < NKVD4) {
    long e = i * 4;
    long r = e >> 11;             // dst row (cols = 2048)
    if (r < 576) cvt4(wkvd, dwkvd, e, e);   // src same linear index while r < 576
    else *(uint2*)(dwkvd + e) = (uint2){0u, 0u};
    return;
  }
  i -= NKVD4;
  if (i < NKVU4) { cvt4(wkvu, dwkvu, i * 4, i * 4); return; }
  i -= NKVU4;
  if (i < NWO4) { cvt4(wo, dwo, i * 4, i * 4); return; }
}

// ---------------- rmsnorm (row per block), bf16 in (+opt fp32 bias), bf16 out ----------------
template<int L>
__global__ __launch_bounds__(256)
void rmsnorm_k(const bf16* __restrict__ in, const float* __restrict__ bias,
               const float* __restrict__ w, bf16* __restrict__ out, int ldin)
{
  constexpr int NIT = L / 256;
  long r = blockIdx.x;
  const bf16* row = in + r * ldin;
  int tid = threadIdx.x;
  float v[NIT];
  float ss = 0.f;
#pragma unroll
  for (int i = 0; i < NIT; ++i) {
    int c = tid + (i << 8);
    float x = __bfloat162float(row[c]) + (bias ? bias[c] : 0.f);
    v[i] = x;
    ss += x * x;
  }
  ss = block_sum(ss);
  float sc = rsqrtf(ss / (float)L + EPSF);
#pragma unroll
  for (int i = 0; i < NIT; ++i) {
    int c = tid + (i << 8);
    out[r * L + c] = __float2bfloat16(v[i] * sc * w[c]);
  }
}

// ---------------- build Q (rope on last 64, pre-scaled by SCALEF) -> (B,NH,S,192) bf16 ----------------
__global__ void build_q(const bf16* __restrict__ Qf, const float* __restrict__ freqs,
                        bf16* __restrict__ Qh)
{
  int idx = blockIdx.x * 256 + threadIdx.x;
  if (idx >= BSD * NHD * 96) return;
  int j = idx % 96;
  int h = (idx / 96) % NHD;
  int srow = idx / (96 * NHD);
  int s = srow & (SSD - 1);
  int b = srow >> 11;
  const bf16* src = Qf + (long)srow * (NHD * QKD) + h * QKD + 2 * j;
  float x0 = __bfloat162float(src[0]), x1 = __bfloat162float(src[1]), y0, y1;
  if (j >= 64) {
    int i = j - 64;
    float f = freqs[s * 32 + i];
    float c, sn;
    __sincosf(f, &sn, &c);
    y0 = x0 * c - x1 * sn;
    y1 = x0 * sn + x1 * c;
  } else { y0 = x0; y1 = x1; }
  bf16* dst = Qh + ((long)(b * NHD + h) * SSD + s) * QKD + 2 * j;
  dst[0] = __float2bfloat16(y0 * SCALEF);
  dst[1] = __float2bfloat16(y1 * SCALEF);
}

// ---------------- build K = [K_nope | rope(K_rope) bcast] -> (B,NH,S,192) bf16 ----------------
__global__ void build_k(const bf16* __restrict__ kvf, const bf16* __restrict__ kvkr,
                        const float* __restrict__ kvb, const float* __restrict__ freqs,
                        bf16* __restrict__ Kh)
{
  int idx = blockIdx.x * 256 + threadIdx.x;
  if (idx >= BSD * NHD * 96) return;
  int j = idx % 96;
  int h = (idx / 96) % NHD;
  int srow = idx / (96 * NHD);
  int s = srow & (SSD - 1);
  int b = srow >> 11;
  float y0, y1;
  if (j < 64) {
    const bf16* src = kvf + (long)srow * 4096 + h * 256 + 2 * j;
    y0 = __bfloat162float(src[0]); y1 = __bfloat162float(src[1]);
  } else {
    int i = j - 64;
    float x0 = __bfloat162float(kvkr[(long)srow * KVPAD + 512 + 2 * i]) + kvb[512 + 2 * i];
    float x1 = __bfloat162float(kvkr[(long)srow * KVPAD + 513 + 2 * i]) + kvb[513 + 2 * i];
    float f = freqs[s * 32 + i];
    float c, sn;
    __sincosf(f, &sn, &c);
    y0 = x0 * c - x1 * sn;
    y1 = x0 * sn + x1 * c;
  }
  bf16* dst = Kh + ((long)(b * NHD + h) * SSD + s) * QKD + 2 * j;
  dst[0] = __float2bfloat16(y0);
  dst[1] = __float2bfloat16(y1);
}

// ---------------- build V^T: kv(B,S,NH,256)[...,128:256] -> Vt (BH,128,S) bf16 ----------------
__global__ __launch_bounds__(256)
void build_vt(const bf16* __restrict__ kvf, bf16* __restrict__ Vt)
{
  __shared__ float t[32][33];
  int s0 = blockIdx.x * 32, d0 = blockIdx.y * 32, z = blockIdx.z;
  int b = z / NHD, h = z % NHD;
  int tx = threadIdx.x, ty = threadIdx.y;  // 32 x 8
#pragma unroll
  for (int r = 0; r < 4; ++r) {
    int sl = ty + r * 8;
    t[sl][tx] = __bfloat162float(kvf[(long)(b * SSD + s0 + sl) * 4096 + h * 256 + 128 + d0 + tx]);
  }
  __syncthreads();
#pragma unroll
  for (int r = 0; r < 4; ++r) {
    int dl = ty + r * 8;
    Vt[((long)z * 128 + d0 + dl) * SSD + s0 + tx] = __float2bfloat16(t[tx][dl]);
  }
}

// ---------------- diagnostic: ws too small ----------------
__global__ void diag_fill(float* out) { out[blockIdx.x * 256 + threadIdx.x] = 1000.0f; }

extern "C" void kernel_launch(void* const* d_in, const int* in_sizes, int n_in,
                              void* d_out, int out_size, void* d_ws, size_t ws_size,
                              hipStream_t stream)
{
  const float* x     = (const float*)d_in[0];
  const float* freqs = (const float*)d_in[1];
  const float* Wqd   = (const float*)d_in[3];
  const float* Wqdb  = (const float*)d_in[4];
  const float* qnw   = (const float*)d_in[5];
  const float* Wqu   = (const float*)d_in[6];
  const float* Wqub  = (const float*)d_in[7];
  const float* Wkvd  = (const float*)d_in[8];
  const float* Wkvdb = (const float*)d_in[9];
  const float* kvnw  = (const float*)d_in[10];
  const float* Wkvu  = (const float*)d_in[11];
  const float* Wkvub = (const float*)d_in[12];
  const float* Wo    = (const float*)d_in[13];
  const float* Wob   = (const float*)d_in[14];
  float* out = (float*)d_out;

  char* ws = (char*)d_ws;
  size_t off = 0;
  auto alloc = [&](size_t bytes) {
    void* p = ws + off;
    off += (bytes + 255) & ~(size_t)255;
    return p;
  };

  bf16* Wqd16  = (bf16*)alloc((size_t)QLORA * DIMD * 2);
  bf16* Wqu16  = (bf16*)alloc((size_t)3072 * QLORA * 2);
  bf16* Wkvd16 = (bf16*)alloc((size_t)KVPAD * DIMD * 2);
  bf16* Wkvu16 = (bf16*)alloc((size_t)4096 * KVLORA * 2);
  bf16* Wo16   = (bf16*)alloc((size_t)DIMD * 2048 * 2);
  bf16* x16    = (bf16*)alloc((size_t)BSD * DIMD * 2);
  bf16* Ra     = (bf16*)alloc((size_t)BSD * QLORA * 2);   // qdown, then kvkr
  bf16* Rb     = (bf16*)alloc((size_t)BSD * QLORA * 2);   // qlat, then kvlat
  bf16* Rc     = (bf16*)alloc((size_t)BSD * 4096 * 2);    // Qf, then kvf, then attnall
  bf16* Qh16   = (bf16*)alloc((size_t)BHN * SSD * QKD * 2);
  bf16* Kh16   = (bf16*)alloc((size_t)BHN * SSD * QKD * 2);
  bf16* Vt16   = (bf16*)alloc((size_t)BHN * 128 * SSD * 2);

  bf16* qdown   = Ra;  bf16* kvkr    = Ra;
  bf16* qlat16  = Rb;  bf16* kvlat16 = Rb;
  bf16* Qf      = Rc;  bf16* kvf     = Rc;  bf16* attnall = Rc;

  if (off > ws_size) { diag_fill<<<8, 256, 0, stream>>>(out); return; }

  dim3 blk(256);
  dim3 blk512(512);
  auto cdiv = [](long a, long b) { return (int)((a + b - 1) / b); };

  // --- all fp32->bf16 converts in one dispatch ---
  long tot4 = NX4 + NQD4 + NQU4 + NKVD4 + NKVU4 + NWO4;
  cvt_all<<<cdiv(tot4, 256), blk, 0, stream>>>(x, Wqd, Wqu, Wkvd, Wkvu, Wo,
                                               x16, Wqd16, Wqu16, Wkvd16, Wkvu16, Wo16);

  // --- Q path (256^2 counted-vmcnt GEMMs) ---
  gemm_bt2<true><<<dim3(QLORA / 256, BSD / 256), blk512, 0, stream>>>(
      x16, Wqd16, Wqdb, qdown, DIMD, QLORA);
  rmsnorm_k<QLORA><<<BSD, blk, 0, stream>>>(qdown, nullptr, qnw, qlat16, QLORA);
  gemm_bt2<true><<<dim3(3072 / 256, BSD / 256), blk512, 0, stream>>>(
      qlat16, Wqu16, Wqub, Qf, QLORA, 3072);
  build_q<<<cdiv((long)BSD * NHD * 96, 256), blk, 0, stream>>>(Qf, freqs, Qh16);

  // --- KV path (down-proj N=640 stays on 128^2 kernel) ---
  gemm_bt<true><<<dim3(KVPAD / 128, BSD / 128, 1), blk, 0, stream>>>(
      x16, Wkvd16, nullptr, kvkr, BSD, KVPAD, DIMD, 0, 0, 0, KVPAD);
  rmsnorm_k<KVLORA><<<BSD, blk, 0, stream>>>(kvkr, Wkvdb, kvnw, kvlat16, KVPAD);
  gemm_bt2<true><<<dim3(4096 / 256, BSD / 256), blk512, 0, stream>>>(
      kvlat16, Wkvu16, Wkvub, kvf, KVLORA, 4096);
  build_k<<<cdiv((long)BSD * NHD * 96, 256), blk, 0, stream>>>(kvf, kvkr, Wkvdb, freqs, Kh16);
  build_vt<<<dim3(SSD / 32, 128 / 32, BHN), dim3(32, 8), 0, stream>>>(kvf, Vt16);

  // --- fused flash attention: 256 two-tile blocks (1/CU), 8 waves each ---
  flash_attn<<<dim3(256), blk512, 0, stream>>>(Qh16, Kh16, Vt16, attnall);

  // --- output projection (fp32 out) ---
  gemm_bt2<false><<<dim3(2048 / 256, BSD / 256), blk512, 0, stream>>>(
      attnall, Wo16, Wob, out, 2048, DIMD);
}

// Round 6
// 527.598 us; speedup vs baseline: 1.1382x; 1.1382x over previous
//
#include <hip/hip_runtime.h>
#include <hip/hip_bf16.h>

#define DIMD 2048
#define NHD 16
#define QLORA 1536
#define KVLORA 512
#define QKD 192
#define BBD 2
#define SSD 2048
#define BSD (BBD*SSD)       // 4096 tokens
#define NDOWN 2176          // fused down-proj width: 1536 (q) + 640 (kv padded)
#define BHN (BBD*NHD)       // 32 (b,h) pairs
#define EPSF 1.1920929e-07f
#define SCALEF 0.07216878364870322f  // 192^-0.5 (folded into Q at build_q)

typedef __hip_bfloat16 bf16;
typedef __attribute__((ext_vector_type(8))) short short8;
typedef __attribute__((ext_vector_type(4))) float floatx4;

typedef __attribute__((address_space(1))) char as1_char;
typedef __attribute__((address_space(3))) char as3_char;
#define GLD16(g, l) __builtin_amdgcn_global_load_lds((as1_char*)(g), (as3_char*)(l), 16, 0, 0)

// ---------------- block reduction (256 threads = 4 waves) ----------------
__device__ __forceinline__ float block_sum(float x) {
#pragma unroll
  for (int o = 32; o > 0; o >>= 1) x += __shfl_xor(x, o, 64);
  __shared__ float red[4];
  __syncthreads();
  if ((threadIdx.x & 63) == 0) red[threadIdx.x >> 6] = x;
  __syncthreads();
  return red[0] + red[1] + red[2] + red[3];
}

// ---------------- generic bf16 MFMA GEMM (128x128 tile):  C = A*B^T + bias ----------------
// R4-verified structure (m97-style: 16KB LDS, ~3 blocks/CU). XCD bijective swizzle.
template<bool STORE_BF16>
__global__ __launch_bounds__(256)
void gemm_bt(const bf16* __restrict__ A, const bf16* __restrict__ Bm,
             const float* __restrict__ bias, void* __restrict__ Cp,
             int M, int N, int K, long sA, long sB, long sC, int ldc)
{
  int nwg = gridDim.x * gridDim.y;
  int lin = blockIdx.y * gridDim.x + blockIdx.x;
  int xcd = lin & 7, l8 = lin >> 3;
  int qd = nwg >> 3, rd = nwg & 7;
  int wg = (xcd < rd ? xcd * (qd + 1) : rd * (qd + 1) + (xcd - rd) * qd) + l8;
  int bx = wg % gridDim.x, by = wg / gridDim.x;

  int m0 = by * 128, n0 = bx * 128;
  long z = blockIdx.z;
  A  += z * sA;
  Bm += z * sB;

  __shared__ __align__(16) bf16 Asm[128 * 32];
  __shared__ __align__(16) bf16 Bsm[128 * 32];

  const int tid  = threadIdx.x;
  const int lane = tid & 63;
  const int wv   = tid >> 6;
  const int wm   = (wv >> 1) << 6;
  const int wn   = (wv & 1) << 6;
  const int fr   = lane & 15;
  const int q8   = (lane >> 4) << 3;

  floatx4 acc[4][4];
#pragma unroll
  for (int i = 0; i < 4; ++i)
#pragma unroll
    for (int j = 0; j < 4; ++j)
      acc[i][j] = (floatx4){0.f, 0.f, 0.f, 0.f};

  for (int k0 = 0; k0 < K; k0 += 32) {
    __syncthreads();
#pragma unroll
    for (int it = 0; it < 2; ++it) {
      int seg = it * 256 + tid;
      int row = seg >> 2, cs = seg & 3;
      GLD16(A  + (long)(m0 + row) * K + k0 + cs * 8, &Asm[(it * 256 + wv * 64) * 8]);
      GLD16(Bm + (long)(n0 + row) * K + k0 + cs * 8, &Bsm[(it * 256 + wv * 64) * 8]);
    }
    __syncthreads();

    short8 fa[4], fb[4];
#pragma unroll
    for (int t = 0; t < 4; ++t) fa[t] = *(const short8*)&Asm[(wm + t * 16 + fr) * 32 + q8];
#pragma unroll
    for (int t = 0; t < 4; ++t) fb[t] = *(const short8*)&Bsm[(wn + t * 16 + fr) * 32 + q8];
#pragma unroll
    for (int i = 0; i < 4; ++i)
#pragma unroll
      for (int j = 0; j < 4; ++j)
        acc[i][j] = __builtin_amdgcn_mfma_f32_16x16x32_bf16(fa[i], fb[j], acc[i][j], 0, 0, 0);
  }

  long cb = z * sC;
  int rq = (lane >> 4) * 4;
#pragma unroll
  for (int i = 0; i < 4; ++i) {
#pragma unroll
    for (int j = 0; j < 4; ++j) {
      int col = n0 + wn + j * 16 + fr;
      float bv = bias ? bias[col] : 0.f;
#pragma unroll
      for (int r = 0; r < 4; ++r) {
        int rowg = m0 + wm + i * 16 + rq + r;
        float v = acc[i][j][r] + bv;
        if (STORE_BF16)
          ((bf16*)Cp)[cb + (long)rowg * ldc + col] = __float2bfloat16(v);
        else
          ((float*)Cp)[cb + (long)rowg * ldc + col] = v;
      }
    }
  }
}

// ---------------- fused flash attention (causal), two tiles per block ----------------
// (byte-identical to R4 -- best verified flash structure)
__global__ __launch_bounds__(512, 2)
void flash_attn(const bf16* __restrict__ Qh, const bf16* __restrict__ Kh,
                const bf16* __restrict__ Vt, bf16* __restrict__ attnall)
{
  const int lin = blockIdx.x;
  const int bh  = lin & 31;
  const int p   = lin >> 5;            // 0..7
  const int qtA = 15 - p;
  const int b = bh >> 4, h = bh & 15;

  const bf16* Qg = Qh + (long)bh * SSD * QKD;
  const bf16* Kg = Kh + (long)bh * SSD * QKD;
  const bf16* Vg = Vt + (long)bh * 128 * SSD;

  __shared__ __align__(16) bf16 SM[57344];
  bf16* KB0 = SM;
  bf16* KB1 = SM + 12288;
  bf16* VB0 = SM + 24576;
  bf16* VB1 = SM + 32768;
  bf16* PB  = SM + 40960;

  const int tid  = threadIdx.x;
  const int lane = tid & 63;
  const int wv   = tid >> 6;       // 0..7
  const int w4   = wv & 3;
  const int tb   = wv >> 2;        // 0 = tile A, 1 = tile B
  const int fr   = lane & 15;
  const int g4   = lane >> 4;

  const int qt    = tb ? (p) : (qtA);
  const int qbase = qt << 7;
  const int jmax  = 2 * qtA + 1;

  long kofs[3]; int kdst[3];
#pragma unroll
  for (int it = 0; it < 3; ++it) {
    int seg = it * 512 + tid;
    int c = seg >> 8, rs = seg & 255;
    int r = rs >> 2, s = (rs & 3) ^ ((r >> 1) & 3);
    kofs[it] = (long)r * QKD + c * 32 + s * 8;
    kdst[it] = c * 2048 + rs * 8;
  }
  long vofs[2]; int vdst[2];
#pragma unroll
  for (int it = 0; it < 2; ++it) {
    int seg = it * 512 + tid;
    int c2 = seg >> 9, ds = seg & 511;
    int d = ds >> 2, s = (ds & 3) ^ ((d >> 1) & 3);
    vofs[it] = (long)d * SSD + c2 * 32 + s * 8;
    vdst[it] = c2 * 4096 + ds * 8;
  }
  int fsw[4];
#pragma unroll
  for (int n = 0; n < 4; ++n) {
    int row = n * 16 + fr;
    fsw[n] = row * 32 + (((g4 ^ (row >> 1)) & 3) << 3);
  }
  int vsw[8];
#pragma unroll
  for (int dn = 0; dn < 8; ++dn) {
    int row = dn * 16 + fr;
    vsw[dn] = row * 32 + (((g4 ^ (row >> 1)) & 3) << 3);
  }
  int qoff[2];
#pragma unroll
  for (int i = 0; i < 2; ++i) {
    int row = wv * 32 + i * 16 + fr;
    qoff[i] = row * 32 + (((g4 ^ (row >> 1)) & 3) << 3);
  }

  const int qbA = qtA << 7, qbB = p << 7;
#pragma unroll
  for (int it = 0; it < 12; ++it) {
    int seg = it * 512 + tid;
    int c = seg >> 10, rs = seg & 1023;
    int r = rs >> 2, s = (rs & 3) ^ ((r >> 1) & 3);
    int grow = (r < 128) ? (qbA + r) : (qbB + r - 128);
    GLD16(Qg + (long)grow * QKD + c * 32 + s * 8, SM + c * 8192 + rs * 8);
  }
  __syncthreads();
  short8 qf[2][6];
#pragma unroll
  for (int i = 0; i < 2; ++i)
#pragma unroll
    for (int c = 0; c < 6; ++c)
      qf[i][c] = *(const short8*)(SM + c * 8192 + qoff[i]);

  floatx4 oacc[2][8];
#pragma unroll
  for (int i = 0; i < 2; ++i)
#pragma unroll
    for (int n = 0; n < 8; ++n) oacc[i][n] = (floatx4){0.f, 0.f, 0.f, 0.f};
  float mi[2][4], li[2][4];
#pragma unroll
  for (int i = 0; i < 2; ++i)
#pragma unroll
    for (int r = 0; r < 4; ++r) { mi[i][r] = -1e30f; li[i][r] = 0.f; }

  __syncthreads();

  auto stageKV = [&](int jb2, bf16* kb2, bf16* vb2) {
#pragma unroll
    for (int it = 0; it < 3; ++it)
      GLD16(Kg + (long)jb2 * QKD + kofs[it], kb2 + kdst[it]);
#pragma unroll
    for (int it = 0; it < 2; ++it)
      GLD16(Vg + jb2 + vofs[it], vb2 + vdst[it]);
  };

  stageKV(0, KB0, VB0);

#pragma unroll 1
  for (int j = 0; j <= jmax; ++j) {
    const int jb = j << 6;
    if (j < jmax) {
      stageKV((j + 1) << 6, (j & 1) ? KB0 : KB1, (j & 1) ? VB0 : VB1);
      asm volatile("s_waitcnt vmcnt(5)" ::: "memory");
    } else {
      asm volatile("s_waitcnt vmcnt(0)" ::: "memory");
    }
    __builtin_amdgcn_sched_barrier(0);
    __builtin_amdgcn_s_barrier();
    __builtin_amdgcn_sched_barrier(0);

    const bf16* kb = (j & 1) ? KB1 : KB0;
    const bf16* vb = (j & 1) ? VB1 : VB0;
    const bool active = (jb <= qbase + w4 * 32 + 31);
    if (active) {
      floatx4 sacc[2][4];
#pragma unroll
      for (int i = 0; i < 2; ++i)
#pragma unroll
        for (int n = 0; n < 4; ++n) sacc[i][n] = (floatx4){0.f, 0.f, 0.f, 0.f};
      __builtin_amdgcn_s_setprio(1);
#pragma unroll
      for (int c = 0; c < 6; ++c) {
#pragma unroll
        for (int n = 0; n < 4; ++n) {
          short8 fb = *(const short8*)(kb + c * 2048 + fsw[n]);
#pragma unroll
          for (int i = 0; i < 2; ++i)
            sacc[i][n] = __builtin_amdgcn_mfma_f32_16x16x32_bf16(qf[i][c], fb, sacc[i][n], 0, 0, 0);
        }
      }
      __builtin_amdgcn_s_setprio(0);

      float pm[2][4];
#pragma unroll
      for (int i = 0; i < 2; ++i) {
        const int rbase = qbase + w4 * 32 + i * 16;
        const bool diag = (jb + 63 > rbase);
#pragma unroll
        for (int r = 0; r < 4; ++r) {
          if (diag) {
            int rowg = rbase + g4 * 4 + r;
#pragma unroll
            for (int n = 0; n < 4; ++n)
              if ((jb + n * 16 + fr) > rowg) sacc[i][n][r] = -1e30f;
          }
          pm[i][r] = fmaxf(fmaxf(sacc[i][0][r], sacc[i][1][r]),
                           fmaxf(sacc[i][2][r], sacc[i][3][r]));
        }
      }
      int nn = 0;
#pragma unroll
      for (int i = 0; i < 2; ++i)
#pragma unroll
        for (int r = 0; r < 4; ++r) nn |= (pm[i][r] > mi[i][r]);
      if (__any(nn)) {
#pragma unroll
        for (int i = 0; i < 2; ++i) {
#pragma unroll
          for (int r = 0; r < 4; ++r) {
            float mx = pm[i][r];
#pragma unroll
            for (int off = 1; off < 16; off <<= 1) mx = fmaxf(mx, __shfl_xor(mx, off, 64));
            float mnew = fmaxf(mi[i][r], mx);
            float alpha = __expf(mi[i][r] - mnew);
            mi[i][r] = mnew;
            li[i][r] *= alpha;
#pragma unroll
            for (int n = 0; n < 8; ++n) oacc[i][n][r] *= alpha;
          }
        }
      }
#pragma unroll
      for (int i = 0; i < 2; ++i) {
#pragma unroll
        for (int r = 0; r < 4; ++r) {
          float acc = 0.f;
#pragma unroll
          for (int n = 0; n < 4; ++n) {
            float pv = __expf(sacc[i][n][r] - mi[i][r]);
            sacc[i][n][r] = pv;
            acc += pv;
          }
          li[i][r] += acc;
        }
      }

#pragma unroll
      for (int i = 0; i < 2; ++i) {
#pragma unroll
        for (int n = 0; n < 4; ++n) {
          int c2 = n >> 1;
          int col = (n & 1) * 16 + fr;
#pragma unroll
          for (int r = 0; r < 4; ++r) {
            int m = wv * 32 + i * 16 + g4 * 4 + r;
            int cw = (((col >> 3) ^ ((m >> 1) & 3)) << 3) | (col & 7);
            PB[c2 * 8192 + m * 32 + cw] = __float2bfloat16(sacc[i][n][r]);
          }
        }
      }

      __builtin_amdgcn_s_setprio(1);
#pragma unroll
      for (int c2 = 0; c2 < 2; ++c2) {
        short8 pf[2];
#pragma unroll
        for (int i = 0; i < 2; ++i)
          pf[i] = *(const short8*)(PB + c2 * 8192 + qoff[i]);
#pragma unroll
        for (int dn = 0; dn < 8; ++dn) {
          short8 vf = *(const short8*)(vb + c2 * 4096 + vsw[dn]);
#pragma unroll
          for (int i = 0; i < 2; ++i)
            oacc[i][dn] = __builtin_amdgcn_mfma_f32_16x16x32_bf16(pf[i], vf, oacc[i][dn], 0, 0, 0);
        }
      }
      __builtin_amdgcn_s_setprio(0);
    }

    __builtin_amdgcn_sched_barrier(0);
    __builtin_amdgcn_s_barrier();
    __builtin_amdgcn_sched_barrier(0);
  }

#pragma unroll
  for (int i = 0; i < 2; ++i) {
#pragma unroll
    for (int r = 0; r < 4; ++r) {
      float l = li[i][r];
#pragma unroll
      for (int off = 1; off < 16; off <<= 1) l += __shfl_xor(l, off, 64);
      float inv = 1.f / l;
      int m = qbase + w4 * 32 + i * 16 + g4 * 4 + r;
      bf16* orow = attnall + ((long)(b * SSD + m) * NHD + h) * 128;
#pragma unroll
      for (int dn = 0; dn < 8; ++dn)
        orow[dn * 16 + fr] = __float2bfloat16(oacc[i][dn][r] * inv);
    }
  }
}

// ---------------- fused fp32 -> bf16 converts (float4-vectorized) ----------------
// Wq_down and Wkv_down are packed into ONE weight matrix Wd[2176][2048]:
// rows 0..1535 = Wq_down, rows 1536..2111 = Wkv_down (576 real), 2112..2175 = 0.
__device__ __forceinline__ void cvt4(const float* __restrict__ s, bf16* __restrict__ d,
                                     long se, long de) {
  float4 v = *(const float4*)(s + se);
  union { bf16 h[4]; uint2 u; } o;
  o.h[0] = __float2bfloat16(v.x); o.h[1] = __float2bfloat16(v.y);
  o.h[2] = __float2bfloat16(v.z); o.h[3] = __float2bfloat16(v.w);
  *(uint2*)(d + de) = o.u;
}

#define NX4   ((long)BSD * DIMD / 4)
#define NQD4  ((long)QLORA * DIMD / 4)
#define NKVD4 ((long)640 * DIMD / 4)
#define NQU4  ((long)3072 * QLORA / 4)
#define NKVU4 ((long)4096 * KVLORA / 4)
#define NWO4  ((long)DIMD * 2048 / 4)

__global__ __launch_bounds__(256)
void cvt_all(const float* __restrict__ x, const float* __restrict__ wqd,
             const float* __restrict__ wkvd, const float* __restrict__ wqu,
             const float* __restrict__ wkvu, const float* __restrict__ wo,
             bf16* __restrict__ dx, bf16* __restrict__ dwd, bf16* __restrict__ dwqu,
             bf16* __restrict__ dwkvu, bf16* __restrict__ dwo)
{
  long i = (long)blockIdx.x * 256 + threadIdx.x;
  if (i < NX4) { cvt4(x, dx, i * 4, i * 4); return; }
  i -= NX4;
  if (i < NQD4) { cvt4(wqd, dwd, i * 4, i * 4); return; }   // q rows of Wd
  i -= NQD4;
  if (i < NKVD4) {                                          // kv rows of Wd (offset 1536 rows)
    long e = i * 4;
    long r = e >> 11;             // kv-local row (cols = 2048)
    if (r < 576) cvt4(wkvd, dwd, e, (long)QLORA * DIMD + e);
    else *(uint2*)(dwd + (long)QLORA * DIMD + e) = (uint2){0u, 0u};
    return;
  }
  i -= NKVD4;
  if (i < NQU4) { cvt4(wqu, dwqu, i * 4, i * 4); return; }
  i -= NQU4;
  if (i < NKVU4) { cvt4(wkvu, dwkvu, i * 4, i * 4); return; }
  i -= NKVU4;
  if (i < NWO4) { cvt4(wo, dwo, i * 4, i * 4); return; }
}

// ---------------- rmsnorm (row per block), bf16 in (+opt fp32 bias), bf16 out ----------------
template<int L>
__global__ __launch_bounds__(256)
void rmsnorm_k(const bf16* __restrict__ in, const float* __restrict__ bias,
               const float* __restrict__ w, bf16* __restrict__ out, int ldin)
{
  constexpr int NIT = L / 256;
  long r = blockIdx.x;
  const bf16* row = in + r * ldin;
  int tid = threadIdx.x;
  float v[NIT];
  float ss = 0.f;
#pragma unroll
  for (int i = 0; i < NIT; ++i) {
    int c = tid + (i << 8);
    float x = __bfloat162float(row[c]) + (bias ? bias[c] : 0.f);
    v[i] = x;
    ss += x * x;
  }
  ss = block_sum(ss);
  float sc = rsqrtf(ss / (float)L + EPSF);
#pragma unroll
  for (int i = 0; i < NIT; ++i) {
    int c = tid + (i << 8);
    out[r * L + c] = __float2bfloat16(v[i] * sc * w[c]);
  }
}

// ---------------- build Q (rope on last 64, pre-scaled by SCALEF) -> (B,NH,S,192) bf16 ----------------
__global__ void build_q(const bf16* __restrict__ Qf, const float* __restrict__ freqs,
                        bf16* __restrict__ Qh)
{
  int idx = blockIdx.x * 256 + threadIdx.x;
  if (idx >= BSD * NHD * 96) return;
  int j = idx % 96;
  int h = (idx / 96) % NHD;
  int srow = idx / (96 * NHD);
  int s = srow & (SSD - 1);
  int b = srow >> 11;
  const bf16* src = Qf + (long)srow * (NHD * QKD) + h * QKD + 2 * j;
  float x0 = __bfloat162float(src[0]), x1 = __bfloat162float(src[1]), y0, y1;
  if (j >= 64) {
    int i = j - 64;
    float f = freqs[s * 32 + i];
    float c, sn;
    __sincosf(f, &sn, &c);
    y0 = x0 * c - x1 * sn;
    y1 = x0 * sn + x1 * c;
  } else { y0 = x0; y1 = x1; }
  bf16* dst = Qh + ((long)(b * NHD + h) * SSD + s) * QKD + 2 * j;
  dst[0] = __float2bfloat16(y0 * SCALEF);
  dst[1] = __float2bfloat16(y1 * SCALEF);
}

// ---------------- build K = [K_nope | rope(K_rope) bcast] -> (B,NH,S,192) bf16 ----------------
// kvkr now lives in the fused down-proj output: row stride NDOWN, K_rope at cols 512..575.
__global__ void build_k(const bf16* __restrict__ kvf, const bf16* __restrict__ kvkr,
                        const float* __restrict__ kvb, const float* __restrict__ freqs,
                        bf16* __restrict__ Kh)
{
  int idx = blockIdx.x * 256 + threadIdx.x;
  if (idx >= BSD * NHD * 96) return;
  int j = idx % 96;
  int h = (idx / 96) % NHD;
  int srow = idx / (96 * NHD);
  int s = srow & (SSD - 1);
  int b = srow >> 11;
  float y0, y1;
  if (j < 64) {
    const bf16* src = kvf + (long)srow * 4096 + h * 256 + 2 * j;
    y0 = __bfloat162float(src[0]); y1 = __bfloat162float(src[1]);
  } else {
    int i = j - 64;
    float x0 = __bfloat162float(kvkr[(long)srow * NDOWN + 512 + 2 * i]) + kvb[512 + 2 * i];
    float x1 = __bfloat162float(kvkr[(long)srow * NDOWN + 513 + 2 * i]) + kvb[513 + 2 * i];
    float f = freqs[s * 32 + i];
    float c, sn;
    __sincosf(f, &sn, &c);
    y0 = x0 * c - x1 * sn;
    y1 = x0 * sn + x1 * c;
  }
  bf16* dst = Kh + ((long)(b * NHD + h) * SSD + s) * QKD + 2 * j;
  dst[0] = __float2bfloat16(y0);
  dst[1] = __float2bfloat16(y1);
}

// ---------------- build V^T: kv(B,S,NH,256)[...,128:256] -> Vt (BH,128,S) bf16 ----------------
__global__ __launch_bounds__(256)
void build_vt(const bf16* __restrict__ kvf, bf16* __restrict__ Vt)
{
  __shared__ float t[32][33];
  int s0 = blockIdx.x * 32, d0 = blockIdx.y * 32, z = blockIdx.z;
  int b = z / NHD, h = z % NHD;
  int tx = threadIdx.x, ty = threadIdx.y;  // 32 x 8
#pragma unroll
  for (int r = 0; r < 4; ++r) {
    int sl = ty + r * 8;
    t[sl][tx] = __bfloat162float(kvf[(long)(b * SSD + s0 + sl) * 4096 + h * 256 + 128 + d0 + tx]);
  }
  __syncthreads();
#pragma unroll
  for (int r = 0; r < 4; ++r) {
    int dl = ty + r * 8;
    Vt[((long)z * 128 + d0 + dl) * SSD + s0 + tx] = __float2bfloat16(t[tx][dl]);
  }
}

// ---------------- diagnostic: ws too small ----------------
__global__ void diag_fill(float* out) { out[blockIdx.x * 256 + threadIdx.x] = 1000.0f; }

extern "C" void kernel_launch(void* const* d_in, const int* in_sizes, int n_in,
                              void* d_out, int out_size, void* d_ws, size_t ws_size,
                              hipStream_t stream)
{
  const float* x     = (const float*)d_in[0];
  const float* freqs = (const float*)d_in[1];
  const float* Wqd   = (const float*)d_in[3];
  const float* Wqdb  = (const float*)d_in[4];
  const float* qnw   = (const float*)d_in[5];
  const float* Wqu   = (const float*)d_in[6];
  const float* Wqub  = (const float*)d_in[7];
  const float* Wkvd  = (const float*)d_in[8];
  const float* Wkvdb = (const float*)d_in[9];
  const float* kvnw  = (const float*)d_in[10];
  const float* Wkvu  = (const float*)d_in[11];
  const float* Wkvub = (const float*)d_in[12];
  const float* Wo    = (const float*)d_in[13];
  const float* Wob   = (const float*)d_in[14];
  float* out = (float*)d_out;

  char* ws = (char*)d_ws;
  size_t off = 0;
  auto alloc = [&](size_t bytes) {
    void* p = ws + off;
    off += (bytes + 255) & ~(size_t)255;
    return p;
  };

  bf16* Wd16   = (bf16*)alloc((size_t)NDOWN * DIMD * 2);   // fused down weights
  bf16* Wqu16  = (bf16*)alloc((size_t)3072 * QLORA * 2);
  bf16* Wkvu16 = (bf16*)alloc((size_t)4096 * KVLORA * 2);
  bf16* Wo16   = (bf16*)alloc((size_t)DIMD * 2048 * 2);
  bf16* x16    = (bf16*)alloc((size_t)BSD * DIMD * 2);
  bf16* Ra     = (bf16*)alloc((size_t)BSD * NDOWN * 2);    // fused down output (qdown | kvkr)
  bf16* Rb     = (bf16*)alloc((size_t)BSD * QLORA * 2);    // qlat, then kvlat
  bf16* Rc     = (bf16*)alloc((size_t)BSD * 4096 * 2);     // Qf, then kvf, then attnall
  bf16* Qh16   = (bf16*)alloc((size_t)BHN * SSD * QKD * 2);
  bf16* Kh16   = (bf16*)alloc((size_t)BHN * SSD * QKD * 2);
  bf16* Vt16   = (bf16*)alloc((size_t)BHN * 128 * SSD * 2);

  bf16* qdown   = Ra;                  // cols 0..1535 of Ra (stride NDOWN)
  bf16* kvkr    = Ra + QLORA;          // cols 1536..2175 of Ra (stride NDOWN)
  bf16* qlat16  = Rb;  bf16* kvlat16 = Rb;
  bf16* Qf      = Rc;  bf16* kvf     = Rc;  bf16* attnall = Rc;

  if (off > ws_size) { diag_fill<<<8, 256, 0, stream>>>(out); return; }

  dim3 blk(256);
  auto cdiv = [](long a, long b) { return (int)((a + b - 1) / b); };

  // --- all fp32->bf16 converts in one dispatch ---
  long tot4 = NX4 + NQD4 + NKVD4 + NQU4 + NKVU4 + NWO4;
  cvt_all<<<cdiv(tot4, 256), blk, 0, stream>>>(x, Wqd, Wkvd, Wqu, Wkvu, Wo,
                                               x16, Wd16, Wqu16, Wkvu16, Wo16);

  // --- fused down-projection: [qdown | kvkr] = x * Wd^T (bias folded into rmsnorm) ---
  gemm_bt<true><<<dim3(NDOWN / 128, BSD / 128, 1), blk, 0, stream>>>(
      x16, Wd16, nullptr, Ra, BSD, NDOWN, DIMD, 0, 0, 0, NDOWN);

  // --- Q path ---
  rmsnorm_k<QLORA><<<BSD, blk, 0, stream>>>(qdown, Wqdb, qnw, qlat16, NDOWN);
  gemm_bt<true><<<dim3(3072 / 128, BSD / 128, 1), blk, 0, stream>>>(
      qlat16, Wqu16, Wqub, Qf, BSD, 3072, QLORA, 0, 0, 0, 3072);
  build_q<<<cdiv((long)BSD * NHD * 96, 256), blk, 0, stream>>>(Qf, freqs, Qh16);

  // --- KV path ---
  rmsnorm_k<KVLORA><<<BSD, blk, 0, stream>>>(kvkr, Wkvdb, kvnw, kvlat16, NDOWN);
  gemm_bt<true><<<dim3(4096 / 128, BSD / 128, 1), blk, 0, stream>>>(
      kvlat16, Wkvu16, Wkvub, kvf, BSD, 4096, KVLORA, 0, 0, 0, 4096);
  build_k<<<cdiv((long)BSD * NHD * 96, 256), blk, 0, stream>>>(kvf, kvkr, Wkvdb, freqs, Kh16);
  build_vt<<<dim3(SSD / 32, 128 / 32, BHN), dim3(32, 8), 0, stream>>>(kvf, Vt16);

  // --- fused flash attention: 256 two-tile blocks (1/CU), 8 waves each ---
  flash_attn<<<dim3(256), dim3(512), 0, stream>>>(Qh16, Kh16, Vt16, attnall);

  // --- output projection (fp32 out) ---
  gemm_bt<false><<<dim3(2048 / 128, BSD / 128, 1), blk, 0, stream>>>(
      attnall, Wo16, Wob, out, BSD, DIMD, 2048, 0, 0, 0, DIMD);
}

// Round 7
// 469.224 us; speedup vs baseline: 1.2798x; 1.1244x over previous
//
#include <hip/hip_runtime.h>
#include <hip/hip_bf16.h>

#define DIMD 2048
#define NHD 16
#define QLORA 1536
#define KVLORA 512
#define QKD 192
#define BBD 2
#define SSD 2048
#define BSD (BBD*SSD)       // 4096 tokens
#define NDOWN 2176          // fused down-proj width: 1536 (q) + 640 (kv padded)
#define BHN (BBD*NHD)       // 32 (b,h) pairs
#define EPSF 1.1920929e-07f
#define SCALEF 0.07216878364870322f  // 192^-0.5 (folded into Q in-register in flash)

typedef __hip_bfloat16 bf16;
typedef __attribute__((ext_vector_type(8))) short short8;
typedef __attribute__((ext_vector_type(4))) float floatx4;

typedef __attribute__((address_space(1))) char as1_char;
typedef __attribute__((address_space(3))) char as3_char;
#define GLD16(g, l) __builtin_amdgcn_global_load_lds((as1_char*)(g), (as3_char*)(l), 16, 0, 0)

// ---------------- block reduction (256 threads = 4 waves) ----------------
__device__ __forceinline__ float block_sum(float x) {
#pragma unroll
  for (int o = 32; o > 0; o >>= 1) x += __shfl_xor(x, o, 64);
  __shared__ float red[4];
  __syncthreads();
  if ((threadIdx.x & 63) == 0) red[threadIdx.x >> 6] = x;
  __syncthreads();
  return red[0] + red[1] + red[2] + red[3];
}

// ---------------- generic bf16 MFMA GEMM (128x128 tile, BK=64):  C = A*B^T + bias ----------------
// m97-style 2-barrier loop but BK=64: 32 MFMA per barrier pair (halves the
// vmcnt(0)-drain frequency vs BK=32). LDS 32KB -> still ~3-4 blocks/CU.
// Seg-XOR swizzle (cs ^= row&7) applied both-sides: pre-swizzled global source
// for global_load_lds (linear LDS dest) + swizzled ds_read -> conflict-free
// b128 fragment reads. XCD bijective swizzle (m204) for L2 locality.
template<bool STORE_BF16>
__global__ __launch_bounds__(256)
void gemm_bt(const bf16* __restrict__ A, const bf16* __restrict__ Bm,
             const float* __restrict__ bias, void* __restrict__ Cp,
             int M, int N, int K, long sA, long sB, long sC, int ldc)
{
  int nwg = gridDim.x * gridDim.y;
  int lin = blockIdx.y * gridDim.x + blockIdx.x;
  int xcd = lin & 7, l8 = lin >> 3;
  int qd = nwg >> 3, rd = nwg & 7;
  int wg = (xcd < rd ? xcd * (qd + 1) : rd * (qd + 1) + (xcd - rd) * qd) + l8;
  int bx = wg % gridDim.x, by = wg / gridDim.x;

  int m0 = by * 128, n0 = bx * 128;
  long z = blockIdx.z;
  A  += z * sA;
  Bm += z * sB;

  __shared__ __align__(16) bf16 Asm[128 * 64];  // 16KB
  __shared__ __align__(16) bf16 Bsm[128 * 64];  // 16KB

  const int tid  = threadIdx.x;
  const int lane = tid & 63;
  const int wv   = tid >> 6;
  const int wm   = (wv >> 1) << 6;
  const int wn   = (wv & 1) << 6;
  const int fr   = lane & 15;
  const int g4   = lane >> 4;

  // staging source offsets (row, swizzled 16B seg) for 4 iterations
  int srow[4]; long sofs[4];
#pragma unroll
  for (int it = 0; it < 4; ++it) {
    int seg = it * 256 + tid;
    int row = seg >> 3, cs = seg & 7;
    srow[it] = row;
    sofs[it] = (long)row * 1 /*placeholder*/;  // recomputed with K below
    (void)cs;
  }
  // fragment read offsets: row*64 + swizzled seg ((ks*4 + g4) ^ (row&7))*8
  int aoff[2][4], boff[2][4];
#pragma unroll
  for (int ks = 0; ks < 2; ++ks) {
#pragma unroll
    for (int t = 0; t < 4; ++t) {
      int ra = wm + t * 16 + fr;
      aoff[ks][t] = ra * 64 + (((ks * 4 + g4) ^ (ra & 7)) << 3);
      int rb = wn + t * 16 + fr;
      boff[ks][t] = rb * 64 + (((ks * 4 + g4) ^ (rb & 7)) << 3);
    }
  }

  floatx4 acc[4][4];
#pragma unroll
  for (int i = 0; i < 4; ++i)
#pragma unroll
    for (int j = 0; j < 4; ++j)
      acc[i][j] = (floatx4){0.f, 0.f, 0.f, 0.f};

  for (int k0 = 0; k0 < K; k0 += 64) {
    __syncthreads();
#pragma unroll
    for (int it = 0; it < 4; ++it) {
      int seg = it * 256 + tid;
      int row = seg >> 3, cs = seg & 7;
      int scs = cs ^ (row & 7);
      GLD16(A  + (long)(m0 + row) * K + k0 + scs * 8, &Asm[(it * 256 + wv * 64) * 8]);
      GLD16(Bm + (long)(n0 + row) * K + k0 + scs * 8, &Bsm[(it * 256 + wv * 64) * 8]);
    }
    __syncthreads();

#pragma unroll
    for (int ks = 0; ks < 2; ++ks) {
      short8 fa[4], fb[4];
#pragma unroll
      for (int t = 0; t < 4; ++t) fa[t] = *(const short8*)&Asm[aoff[ks][t]];
#pragma unroll
      for (int t = 0; t < 4; ++t) fb[t] = *(const short8*)&Bsm[boff[ks][t]];
      __builtin_amdgcn_s_setprio(1);
#pragma unroll
      for (int i = 0; i < 4; ++i)
#pragma unroll
        for (int j = 0; j < 4; ++j)
          acc[i][j] = __builtin_amdgcn_mfma_f32_16x16x32_bf16(fa[i], fb[j], acc[i][j], 0, 0, 0);
      __builtin_amdgcn_s_setprio(0);
    }
  }

  long cb = z * sC;
  int rq = g4 * 4;
#pragma unroll
  for (int i = 0; i < 4; ++i) {
#pragma unroll
    for (int j = 0; j < 4; ++j) {
      int col = n0 + wn + j * 16 + fr;
      float bv = bias ? bias[col] : 0.f;
#pragma unroll
      for (int r = 0; r < 4; ++r) {
        int rowg = m0 + wm + i * 16 + rq + r;
        float v = acc[i][j][r] + bv;
        if (STORE_BF16)
          ((bf16*)Cp)[cb + (long)rowg * ldc + col] = __float2bfloat16(v);
        else
          ((float*)Cp)[cb + (long)rowg * ldc + col] = v;
      }
    }
  }
}

// ---------------- fused flash attention (causal), two tiles per block ----------------
// R4-verified loop structure. NEW: Q is staged directly from Qf (B,S,NH*192)
// (row stride 3072, per-head offset) and rope+SCALEF are applied IN-REGISTER to
// the qf fragments once per block -- build_q and the Qh buffer are eliminated.
__global__ __launch_bounds__(512, 2)
void flash_attn(const bf16* __restrict__ Qf, const bf16* __restrict__ Kh,
                const bf16* __restrict__ Vt, const float* __restrict__ freqs,
                bf16* __restrict__ attnall)
{
  const int lin = blockIdx.x;
  const int bh  = lin & 31;
  const int p   = lin >> 5;            // 0..7
  const int qtA = 15 - p;
  const int b = bh >> 4, h = bh & 15;

  const bf16* Qgf = Qf + (long)b * SSD * 3072 + h * QKD;   // (s) stride 3072
  const bf16* Kg  = Kh + (long)bh * SSD * QKD;
  const bf16* Vg  = Vt + (long)bh * 128 * SSD;

  __shared__ __align__(16) bf16 SM[57344];
  bf16* KB0 = SM;
  bf16* KB1 = SM + 12288;
  bf16* VB0 = SM + 24576;
  bf16* VB1 = SM + 32768;
  bf16* PB  = SM + 40960;

  const int tid  = threadIdx.x;
  const int lane = tid & 63;
  const int wv   = tid >> 6;       // 0..7
  const int w4   = wv & 3;
  const int tb   = wv >> 2;        // 0 = tile A, 1 = tile B
  const int fr   = lane & 15;
  const int g4   = lane >> 4;

  const int qt    = tb ? (p) : (qtA);
  const int qbase = qt << 7;
  const int jmax  = 2 * qtA + 1;

  long kofs[3]; int kdst[3];
#pragma unroll
  for (int it = 0; it < 3; ++it) {
    int seg = it * 512 + tid;
    int c = seg >> 8, rs = seg & 255;
    int r = rs >> 2, s = (rs & 3) ^ ((r >> 1) & 3);
    kofs[it] = (long)r * QKD + c * 32 + s * 8;
    kdst[it] = c * 2048 + rs * 8;
  }
  long vofs[2]; int vdst[2];
#pragma unroll
  for (int it = 0; it < 2; ++it) {
    int seg = it * 512 + tid;
    int c2 = seg >> 9, ds = seg & 511;
    int d = ds >> 2, s = (ds & 3) ^ ((d >> 1) & 3);
    vofs[it] = (long)d * SSD + c2 * 32 + s * 8;
    vdst[it] = c2 * 4096 + ds * 8;
  }
  int fsw[4];
#pragma unroll
  for (int n = 0; n < 4; ++n) {
    int row = n * 16 + fr;
    fsw[n] = row * 32 + (((g4 ^ (row >> 1)) & 3) << 3);
  }
  int vsw[8];
#pragma unroll
  for (int dn = 0; dn < 8; ++dn) {
    int row = dn * 16 + fr;
    vsw[dn] = row * 32 + (((g4 ^ (row >> 1)) & 3) << 3);
  }
  int qoff[2];
#pragma unroll
  for (int i = 0; i < 2; ++i) {
    int row = wv * 32 + i * 16 + fr;
    qoff[i] = row * 32 + (((g4 ^ (row >> 1)) & 3) << 3);
  }

  // --- stage both Q tiles (96KB) straight from Qf ---
  const int qbA = qtA << 7, qbB = p << 7;
#pragma unroll
  for (int it = 0; it < 12; ++it) {
    int seg = it * 512 + tid;
    int c = seg >> 10, rs = seg & 1023;
    int r = rs >> 2, s = (rs & 3) ^ ((r >> 1) & 3);
    int tok = (r < 128) ? (qbA + r) : (qbB + r - 128);
    GLD16(Qgf + (long)tok * 3072 + c * 32 + s * 8, SM + c * 8192 + rs * 8);
  }
  __syncthreads();
  short8 qf[2][6];
#pragma unroll
  for (int i = 0; i < 2; ++i)
#pragma unroll
    for (int c = 0; c < 6; ++c)
      qf[i][c] = *(const short8*)(SM + c * 8192 + qoff[i]);

  // --- apply SCALEF (cols 0..127) and rope+SCALEF (cols 128..191) in-register ---
#pragma unroll
  for (int i = 0; i < 2; ++i) {
    int tok = qbase + w4 * 32 + i * 16 + fr;
    const float* fq = freqs + (long)tok * 32;
#pragma unroll
    for (int c = 0; c < 4; ++c) {
#pragma unroll
      for (int e = 0; e < 8; ++e) {
        bf16* el = (bf16*)&qf[i][c];
        el[e] = __float2bfloat16(__bfloat162float(el[e]) * SCALEF);
      }
    }
#pragma unroll
    for (int c = 4; c < 6; ++c) {
#pragma unroll
      for (int pp = 0; pp < 4; ++pp) {
        int jj = (c - 4) * 16 + g4 * 4 + pp;
        float f = fq[jj];
        float cs, sn;
        __sincosf(f, &sn, &cs);
        bf16* el = (bf16*)&qf[i][c];
        float x0 = __bfloat162float(el[2 * pp]);
        float x1 = __bfloat162float(el[2 * pp + 1]);
        el[2 * pp]     = __float2bfloat16((x0 * cs - x1 * sn) * SCALEF);
        el[2 * pp + 1] = __float2bfloat16((x0 * sn + x1 * cs) * SCALEF);
      }
    }
  }

  floatx4 oacc[2][8];
#pragma unroll
  for (int i = 0; i < 2; ++i)
#pragma unroll
    for (int n = 0; n < 8; ++n) oacc[i][n] = (floatx4){0.f, 0.f, 0.f, 0.f};
  float mi[2][4], li[2][4];
#pragma unroll
  for (int i = 0; i < 2; ++i)
#pragma unroll
    for (int r = 0; r < 4; ++r) { mi[i][r] = -1e30f; li[i][r] = 0.f; }

  __syncthreads();

  auto stageKV = [&](int jb2, bf16* kb2, bf16* vb2) {
#pragma unroll
    for (int it = 0; it < 3; ++it)
      GLD16(Kg + (long)jb2 * QKD + kofs[it], kb2 + kdst[it]);
#pragma unroll
    for (int it = 0; it < 2; ++it)
      GLD16(Vg + jb2 + vofs[it], vb2 + vdst[it]);
  };

  stageKV(0, KB0, VB0);

#pragma unroll 1
  for (int j = 0; j <= jmax; ++j) {
    const int jb = j << 6;
    if (j < jmax) {
      stageKV((j + 1) << 6, (j & 1) ? KB0 : KB1, (j & 1) ? VB0 : VB1);
      asm volatile("s_waitcnt vmcnt(5)" ::: "memory");
    } else {
      asm volatile("s_waitcnt vmcnt(0)" ::: "memory");
    }
    __builtin_amdgcn_sched_barrier(0);
    __builtin_amdgcn_s_barrier();
    __builtin_amdgcn_sched_barrier(0);

    const bf16* kb = (j & 1) ? KB1 : KB0;
    const bf16* vb = (j & 1) ? VB1 : VB0;
    const bool active = (jb <= qbase + w4 * 32 + 31);
    if (active) {
      floatx4 sacc[2][4];
#pragma unroll
      for (int i = 0; i < 2; ++i)
#pragma unroll
        for (int n = 0; n < 4; ++n) sacc[i][n] = (floatx4){0.f, 0.f, 0.f, 0.f};
      __builtin_amdgcn_s_setprio(1);
#pragma unroll
      for (int c = 0; c < 6; ++c) {
#pragma unroll
        for (int n = 0; n < 4; ++n) {
          short8 fb = *(const short8*)(kb + c * 2048 + fsw[n]);
#pragma unroll
          for (int i = 0; i < 2; ++i)
            sacc[i][n] = __builtin_amdgcn_mfma_f32_16x16x32_bf16(qf[i][c], fb, sacc[i][n], 0, 0, 0);
        }
      }
      __builtin_amdgcn_s_setprio(0);

      float pm[2][4];
#pragma unroll
      for (int i = 0; i < 2; ++i) {
        const int rbase = qbase + w4 * 32 + i * 16;
        const bool diag = (jb + 63 > rbase);
#pragma unroll
        for (int r = 0; r < 4; ++r) {
          if (diag) {
            int rowg = rbase + g4 * 4 + r;
#pragma unroll
            for (int n = 0; n < 4; ++n)
              if ((jb + n * 16 + fr) > rowg) sacc[i][n][r] = -1e30f;
          }
          pm[i][r] = fmaxf(fmaxf(sacc[i][0][r], sacc[i][1][r]),
                           fmaxf(sacc[i][2][r], sacc[i][3][r]));
        }
      }
      int nn = 0;
#pragma unroll
      for (int i = 0; i < 2; ++i)
#pragma unroll
        for (int r = 0; r < 4; ++r) nn |= (pm[i][r] > mi[i][r]);
      if (__any(nn)) {
#pragma unroll
        for (int i = 0; i < 2; ++i) {
#pragma unroll
          for (int r = 0; r < 4; ++r) {
            float mx = pm[i][r];
#pragma unroll
            for (int off = 1; off < 16; off <<= 1) mx = fmaxf(mx, __shfl_xor(mx, off, 64));
            float mnew = fmaxf(mi[i][r], mx);
            float alpha = __expf(mi[i][r] - mnew);
            mi[i][r] = mnew;
            li[i][r] *= alpha;
#pragma unroll
            for (int n = 0; n < 8; ++n) oacc[i][n][r] *= alpha;
          }
        }
      }
#pragma unroll
      for (int i = 0; i < 2; ++i) {
#pragma unroll
        for (int r = 0; r < 4; ++r) {
          float acc = 0.f;
#pragma unroll
          for (int n = 0; n < 4; ++n) {
            float pv = __expf(sacc[i][n][r] - mi[i][r]);
            sacc[i][n][r] = pv;
            acc += pv;
          }
          li[i][r] += acc;
        }
      }

#pragma unroll
      for (int i = 0; i < 2; ++i) {
#pragma unroll
        for (int n = 0; n < 4; ++n) {
          int c2 = n >> 1;
          int col = (n & 1) * 16 + fr;
#pragma unroll
          for (int r = 0; r < 4; ++r) {
            int m = wv * 32 + i * 16 + g4 * 4 + r;
            int cw = (((col >> 3) ^ ((m >> 1) & 3)) << 3) | (col & 7);
            PB[c2 * 8192 + m * 32 + cw] = __float2bfloat16(sacc[i][n][r]);
          }
        }
      }

      __builtin_amdgcn_s_setprio(1);
#pragma unroll
      for (int c2 = 0; c2 < 2; ++c2) {
        short8 pf[2];
#pragma unroll
        for (int i = 0; i < 2; ++i)
          pf[i] = *(const short8*)(PB + c2 * 8192 + qoff[i]);
#pragma unroll
        for (int dn = 0; dn < 8; ++dn) {
          short8 vf = *(const short8*)(vb + c2 * 4096 + vsw[dn]);
#pragma unroll
          for (int i = 0; i < 2; ++i)
            oacc[i][dn] = __builtin_amdgcn_mfma_f32_16x16x32_bf16(pf[i], vf, oacc[i][dn], 0, 0, 0);
        }
      }
      __builtin_amdgcn_s_setprio(0);
    }

    __builtin_amdgcn_sched_barrier(0);
    __builtin_amdgcn_s_barrier();
    __builtin_amdgcn_sched_barrier(0);
  }

#pragma unroll
  for (int i = 0; i < 2; ++i) {
#pragma unroll
    for (int r = 0; r < 4; ++r) {
      float l = li[i][r];
#pragma unroll
      for (int off = 1; off < 16; off <<= 1) l += __shfl_xor(l, off, 64);
      float inv = 1.f / l;
      int m = qbase + w4 * 32 + i * 16 + g4 * 4 + r;
      bf16* orow = attnall + ((long)(b * SSD + m) * NHD + h) * 128;
#pragma unroll
      for (int dn = 0; dn < 8; ++dn)
        orow[dn * 16 + fr] = __float2bfloat16(oacc[i][dn][r] * inv);
    }
  }
}

// ---------------- fused fp32 -> bf16 converts (float4-vectorized) ----------------
// Wq_down and Wkv_down are packed into ONE weight matrix Wd[2176][2048]:
// rows 0..1535 = Wq_down, rows 1536..2111 = Wkv_down (576 real), 2112..2175 = 0.
__device__ __forceinline__ void cvt4(const float* __restrict__ s, bf16* __restrict__ d,
                                     long se, long de) {
  float4 v = *(const float4*)(s + se);
  union { bf16 h[4]; uint2 u; } o;
  o.h[0] = __float2bfloat16(v.x); o.h[1] = __float2bfloat16(v.y);
  o.h[2] = __float2bfloat16(v.z); o.h[3] = __float2bfloat16(v.w);
  *(uint2*)(d + de) = o.u;
}

#define NX4   ((long)BSD * DIMD / 4)
#define NQD4  ((long)QLORA * DIMD / 4)
#define NKVD4 ((long)640 * DIMD / 4)
#define NQU4  ((long)3072 * QLORA / 4)
#define NKVU4 ((long)4096 * KVLORA / 4)
#define NWO4  ((long)DIMD * 2048 / 4)

__global__ __launch_bounds__(256)
void cvt_all(const float* __restrict__ x, const float* __restrict__ wqd,
             const float* __restrict__ wkvd, const float* __restrict__ wqu,
             const float* __restrict__ wkvu, const float* __restrict__ wo,
             bf16* __restrict__ dx, bf16* __restrict__ dwd, bf16* __restrict__ dwqu,
             bf16* __restrict__ dwkvu, bf16* __restrict__ dwo)
{
  long i = (long)blockIdx.x * 256 + threadIdx.x;
  if (i < NX4) { cvt4(x, dx, i * 4, i * 4); return; }
  i -= NX4;
  if (i < NQD4) { cvt4(wqd, dwd, i * 4, i * 4); return; }   // q rows of Wd
  i -= NQD4;
  if (i < NKVD4) {                                          // kv rows of Wd (offset 1536 rows)
    long e = i * 4;
    long r = e >> 11;             // kv-local row (cols = 2048)
    if (r < 576) cvt4(wkvd, dwd, e, (long)QLORA * DIMD + e);
    else *(uint2*)(dwd + (long)QLORA * DIMD + e) = (uint2){0u, 0u};
    return;
  }
  i -= NKVD4;
  if (i < NQU4) { cvt4(wqu, dwqu, i * 4, i * 4); return; }
  i -= NQU4;
  if (i < NKVU4) { cvt4(wkvu, dwkvu, i * 4, i * 4); return; }
  i -= NKVU4;
  if (i < NWO4) { cvt4(wo, dwo, i * 4, i * 4); return; }
}

// ---------------- rmsnorm (row per block), bf16 in (+opt fp32 bias), bf16 out ----------------
template<int L>
__global__ __launch_bounds__(256)
void rmsnorm_k(const bf16* __restrict__ in, const float* __restrict__ bias,
               const float* __restrict__ w, bf16* __restrict__ out, int ldin)
{
  constexpr int NIT = L / 256;
  long r = blockIdx.x;
  const bf16* row = in + r * ldin;
  int tid = threadIdx.x;
  float v[NIT];
  float ss = 0.f;
#pragma unroll
  for (int i = 0; i < NIT; ++i) {
    int c = tid + (i << 8);
    float x = __bfloat162float(row[c]) + (bias ? bias[c] : 0.f);
    v[i] = x;
    ss += x * x;
  }
  ss = block_sum(ss);
  float sc = rsqrtf(ss / (float)L + EPSF);
#pragma unroll
  for (int i = 0; i < NIT; ++i) {
    int c = tid + (i << 8);
    out[r * L + c] = __float2bfloat16(v[i] * sc * w[c]);
  }
}

// ---------------- build K = [K_nope | rope(K_rope) bcast] -> (B,NH,S,192) bf16 ----------------
// kvkr lives in the fused down-proj output: row stride NDOWN, K_rope at cols 512..575.
__global__ void build_k(const bf16* __restrict__ kvf, const bf16* __restrict__ kvkr,
                        const float* __restrict__ kvb, const float* __restrict__ freqs,
                        bf16* __restrict__ Kh)
{
  int idx = blockIdx.x * 256 + threadIdx.x;
  if (idx >= BSD * NHD * 96) return;
  int j = idx % 96;
  int h = (idx / 96) % NHD;
  int srow = idx / (96 * NHD);
  int s = srow & (SSD - 1);
  int b = srow >> 11;
  float y0, y1;
  if (j < 64) {
    const bf16* src = kvf + (long)srow * 4096 + h * 256 + 2 * j;
    y0 = __bfloat162float(src[0]); y1 = __bfloat162float(src[1]);
  } else {
    int i = j - 64;
    float x0 = __bfloat162float(kvkr[(long)srow * NDOWN + 512 + 2 * i]) + kvb[512 + 2 * i];
    float x1 = __bfloat162float(kvkr[(long)srow * NDOWN + 513 + 2 * i]) + kvb[513 + 2 * i];
    float f = freqs[s * 32 + i];
    float c, sn;
    __sincosf(f, &sn, &c);
    y0 = x0 * c - x1 * sn;
    y1 = x0 * sn + x1 * c;
  }
  bf16* dst = Kh + ((long)(b * NHD + h) * SSD + s) * QKD + 2 * j;
  dst[0] = __float2bfloat16(y0);
  dst[1] = __float2bfloat16(y1);
}

// ---------------- build V^T: kv(B,S,NH,256)[...,128:256] -> Vt (BH,128,S) bf16 ----------------
__global__ __launch_bounds__(256)
void build_vt(const bf16* __restrict__ kvf, bf16* __restrict__ Vt)
{
  __shared__ float t[32][33];
  int s0 = blockIdx.x * 32, d0 = blockIdx.y * 32, z = blockIdx.z;
  int b = z / NHD, h = z % NHD;
  int tx = threadIdx.x, ty = threadIdx.y;  // 32 x 8
#pragma unroll
  for (int r = 0; r < 4; ++r) {
    int sl = ty + r * 8;
    t[sl][tx] = __bfloat162float(kvf[(long)(b * SSD + s0 + sl) * 4096 + h * 256 + 128 + d0 + tx]);
  }
  __syncthreads();
#pragma unroll
  for (int r = 0; r < 4; ++r) {
    int dl = ty + r * 8;
    Vt[((long)z * 128 + d0 + dl) * SSD + s0 + tx] = __float2bfloat16(t[tx][dl]);
  }
}

// ---------------- diagnostic: ws too small ----------------
__global__ void diag_fill(float* out) { out[blockIdx.x * 256 + threadIdx.x] = 1000.0f; }

extern "C" void kernel_launch(void* const* d_in, const int* in_sizes, int n_in,
                              void* d_out, int out_size, void* d_ws, size_t ws_size,
                              hipStream_t stream)
{
  const float* x     = (const float*)d_in[0];
  const float* freqs = (const float*)d_in[1];
  const float* Wqd   = (const float*)d_in[3];
  const float* Wqdb  = (const float*)d_in[4];
  const float* qnw   = (const float*)d_in[5];
  const float* Wqu   = (const float*)d_in[6];
  const float* Wqub  = (const float*)d_in[7];
  const float* Wkvd  = (const float*)d_in[8];
  const float* Wkvdb = (const float*)d_in[9];
  const float* kvnw  = (const float*)d_in[10];
  const float* Wkvu  = (const float*)d_in[11];
  const float* Wkvub = (const float*)d_in[12];
  const float* Wo    = (const float*)d_in[13];
  const float* Wob   = (const float*)d_in[14];
  float* out = (float*)d_out;

  char* ws = (char*)d_ws;
  size_t off = 0;
  auto alloc = [&](size_t bytes) {
    void* p = ws + off;
    off += (bytes + 255) & ~(size_t)255;
    return p;
  };

  bf16* Wd16   = (bf16*)alloc((size_t)NDOWN * DIMD * 2);   // fused down weights
  bf16* Wqu16  = (bf16*)alloc((size_t)3072 * QLORA * 2);
  bf16* Wkvu16 = (bf16*)alloc((size_t)4096 * KVLORA * 2);
  bf16* Wo16   = (bf16*)alloc((size_t)DIMD * 2048 * 2);
  bf16* x16    = (bf16*)alloc((size_t)BSD * DIMD * 2);
  bf16* Ra     = (bf16*)alloc((size_t)BSD * NDOWN * 2);    // fused down output (qdown | kvkr)
  bf16* Rb     = (bf16*)alloc((size_t)BSD * QLORA * 2);    // qlat, then kvlat
  bf16* Rc     = (bf16*)alloc((size_t)BSD * 4096 * 2);     // Qf, then kvf, then attnall
  bf16* Qf     = (bf16*)alloc((size_t)BSD * 3072 * 2);     // Q up-proj output (read by flash)
  bf16* Kh16   = (bf16*)alloc((size_t)BHN * SSD * QKD * 2);
  bf16* Vt16   = (bf16*)alloc((size_t)BHN * 128 * SSD * 2);

  bf16* qdown   = Ra;                  // cols 0..1535 of Ra (stride NDOWN)
  bf16* kvkr    = Ra + QLORA;          // cols 1536..2175 of Ra (stride NDOWN)
  bf16* qlat16  = Rb;  bf16* kvlat16 = Rb;
  bf16* kvf     = Rc;  bf16* attnall = Rc;

  if (off > ws_size) { diag_fill<<<8, 256, 0, stream>>>(out); return; }

  dim3 blk(256);
  auto cdiv = [](long a, long b) { return (int)((a + b - 1) / b); };

  // --- all fp32->bf16 converts in one dispatch ---
  long tot4 = NX4 + NQD4 + NKVD4 + NQU4 + NKVU4 + NWO4;
  cvt_all<<<cdiv(tot4, 256), blk, 0, stream>>>(x, Wqd, Wkvd, Wqu, Wkvu, Wo,
                                               x16, Wd16, Wqu16, Wkvu16, Wo16);

  // --- fused down-projection: [qdown | kvkr] = x * Wd^T (bias folded into rmsnorm) ---
  gemm_bt<true><<<dim3(NDOWN / 128, BSD / 128, 1), blk, 0, stream>>>(
      x16, Wd16, nullptr, Ra, BSD, NDOWN, DIMD, 0, 0, 0, NDOWN);

  // --- Q path (rope+scale now applied inside flash; no build_q) ---
  rmsnorm_k<QLORA><<<BSD, blk, 0, stream>>>(qdown, Wqdb, qnw, qlat16, NDOWN);
  gemm_bt<true><<<dim3(3072 / 128, BSD / 128, 1), blk, 0, stream>>>(
      qlat16, Wqu16, Wqub, Qf, BSD, 3072, QLORA, 0, 0, 0, 3072);

  // --- KV path ---
  rmsnorm_k<KVLORA><<<BSD, blk, 0, stream>>>(kvkr, Wkvdb, kvnw, kvlat16, NDOWN);
  gemm_bt<true><<<dim3(4096 / 128, BSD / 128, 1), blk, 0, stream>>>(
      kvlat16, Wkvu16, Wkvub, kvf, BSD, 4096, KVLORA, 0, 0, 0, 4096);
  build_k<<<cdiv((long)BSD * NHD * 96, 256), blk, 0, stream>>>(kvf, kvkr, Wkvdb, freqs, Kh16);
  build_vt<<<dim3(SSD / 32, 128 / 32, BHN), dim3(32, 8), 0, stream>>>(kvf, Vt16);

  // --- fused flash attention: 256 two-tile blocks (1/CU), 8 waves each ---
  flash_attn<<<dim3(256), dim3(512), 0, stream>>>(Qf, Kh16, Vt16, freqs, attnall);

  // --- output projection (fp32 out) ---
  gemm_bt<false><<<dim3(2048 / 128, BSD / 128, 1), blk, 0, stream>>>(
      attnall, Wo16, Wob, out, BSD, DIMD, 2048, 0, 0, 0, DIMD);
}

// Round 8
// 457.373 us; speedup vs baseline: 1.3129x; 1.0259x over previous
//
#include <hip/hip_runtime.h>
#include <hip/hip_bf16.h>

#define DIMD 2048
#define NHD 16
#define QLORA 1536
#define KVLORA 512
#define QKD 192
#define BBD 2
#define SSD 2048
#define BSD (BBD*SSD)       // 4096 tokens
#define NDOWN 2176          // fused down-proj width: 1536 (q) + 640 (kv padded)
#define BHN (BBD*NHD)       // 32 (b,h) pairs
#define EPSF 1.1920929e-07f
#define SCALEF 0.07216878364870322f  // 192^-0.5 (applied in-register in flash)

typedef __hip_bfloat16 bf16;
typedef __attribute__((ext_vector_type(8))) short short8;
typedef __attribute__((ext_vector_type(4))) float floatx4;

typedef __attribute__((address_space(1))) char as1_char;
typedef __attribute__((address_space(3))) char as3_char;
#define GLD16(g, l) __builtin_amdgcn_global_load_lds((as1_char*)(g), (as3_char*)(l), 16, 0, 0)

// ---------------- block reduction (256 threads = 4 waves) ----------------
__device__ __forceinline__ float block_sum(float x) {
#pragma unroll
  for (int o = 32; o > 0; o >>= 1) x += __shfl_xor(x, o, 64);
  __shared__ float red[4];
  __syncthreads();
  if ((threadIdx.x & 63) == 0) red[threadIdx.x >> 6] = x;
  __syncthreads();
  return red[0] + red[1] + red[2] + red[3];
}

// ---------------- generic bf16 MFMA GEMM (128x128 tile, BK=64):  C = A*B^T + bias ----------------
// R7-verified structure: single-buffer BK=64, seg-XOR swizzle both-sides, XCD swizzle.
// MODE 0: f32 out (ldc). MODE 1: bf16 out (ldc).
// MODE 2: kv-split -- K_nope col-blocks (n0&128==0) go head-major into Kh
//         (B,NH,S,192 cols 0..127); V col-blocks go to Cp (kvf, ldc).
// MODE 3: q head-major -- write bf16 to Cp=(B,NH,S,192) via h=col/192, jj=col%192.
template<int MODE>
__global__ __launch_bounds__(256)
void gemm_bt(const bf16* __restrict__ A, const bf16* __restrict__ Bm,
             const float* __restrict__ bias, void* __restrict__ Cp,
             int K, int ldc, bf16* __restrict__ Kh)
{
  int nwg = gridDim.x * gridDim.y;
  int lin = blockIdx.y * gridDim.x + blockIdx.x;
  int xcd = lin & 7, l8 = lin >> 3;
  int qd = nwg >> 3, rd = nwg & 7;
  int wg = (xcd < rd ? xcd * (qd + 1) : rd * (qd + 1) + (xcd - rd) * qd) + l8;
  int bx = wg % gridDim.x, by = wg / gridDim.x;

  int m0 = by * 128, n0 = bx * 128;

  __shared__ __align__(16) bf16 Asm[128 * 64];  // 16KB
  __shared__ __align__(16) bf16 Bsm[128 * 64];  // 16KB

  const int tid  = threadIdx.x;
  const int lane = tid & 63;
  const int wv   = tid >> 6;
  const int wm   = (wv >> 1) << 6;
  const int wn   = (wv & 1) << 6;
  const int fr   = lane & 15;
  const int g4   = lane >> 4;

  // fragment read offsets: row*64 + swizzled seg ((ks*4 + g4) ^ (row&7))*8
  int aoff[2][4], boff[2][4];
#pragma unroll
  for (int ks = 0; ks < 2; ++ks) {
#pragma unroll
    for (int t = 0; t < 4; ++t) {
      int ra = wm + t * 16 + fr;
      aoff[ks][t] = ra * 64 + (((ks * 4 + g4) ^ (ra & 7)) << 3);
      int rb = wn + t * 16 + fr;
      boff[ks][t] = rb * 64 + (((ks * 4 + g4) ^ (rb & 7)) << 3);
    }
  }

  floatx4 acc[4][4];
#pragma unroll
  for (int i = 0; i < 4; ++i)
#pragma unroll
    for (int j = 0; j < 4; ++j)
      acc[i][j] = (floatx4){0.f, 0.f, 0.f, 0.f};

  for (int k0 = 0; k0 < K; k0 += 64) {
    __syncthreads();
#pragma unroll
    for (int it = 0; it < 4; ++it) {
      int seg = it * 256 + tid;
      int row = seg >> 3, cs = seg & 7;
      int scs = cs ^ (row & 7);
      GLD16(A  + (long)(m0 + row) * K + k0 + scs * 8, &Asm[(it * 256 + wv * 64) * 8]);
      GLD16(Bm + (long)(n0 + row) * K + k0 + scs * 8, &Bsm[(it * 256 + wv * 64) * 8]);
    }
    __syncthreads();

#pragma unroll
    for (int ks = 0; ks < 2; ++ks) {
      short8 fa[4], fb[4];
#pragma unroll
      for (int t = 0; t < 4; ++t) fa[t] = *(const short8*)&Asm[aoff[ks][t]];
#pragma unroll
      for (int t = 0; t < 4; ++t) fb[t] = *(const short8*)&Bsm[boff[ks][t]];
      __builtin_amdgcn_s_setprio(1);
#pragma unroll
      for (int i = 0; i < 4; ++i)
#pragma unroll
        for (int j = 0; j < 4; ++j)
          acc[i][j] = __builtin_amdgcn_mfma_f32_16x16x32_bf16(fa[i], fb[j], acc[i][j], 0, 0, 0);
      __builtin_amdgcn_s_setprio(0);
    }
  }

  const int rq = g4 * 4;
  const bool kvK = (MODE == 2) && ((n0 & 128) == 0);
  const int kvh = n0 >> 8;
#pragma unroll
  for (int i = 0; i < 4; ++i) {
#pragma unroll
    for (int j = 0; j < 4; ++j) {
      int col = n0 + wn + j * 16 + fr;
      float bv = bias ? bias[col] : 0.f;
#pragma unroll
      for (int r = 0; r < 4; ++r) {
        int rowg = m0 + wm + i * 16 + rq + r;
        float v = acc[i][j][r] + bv;
        if (MODE == 0) {
          ((float*)Cp)[(long)rowg * ldc + col] = v;
        } else if (MODE == 1) {
          ((bf16*)Cp)[(long)rowg * ldc + col] = __float2bfloat16(v);
        } else if (MODE == 2) {
          if (kvK) {
            int bb = rowg >> 11, s = rowg & (SSD - 1);
            int jj = col & 255;
            Kh[((long)(bb * NHD + kvh) * SSD + s) * QKD + jj] = __float2bfloat16(v);
          } else {
            ((bf16*)Cp)[(long)rowg * ldc + col] = __float2bfloat16(v);
          }
        } else {  // MODE 3: head-major Q
          unsigned h = (unsigned)col / 192u;
          int jj = col - (int)h * 192;
          int bb = rowg >> 11, s = rowg & (SSD - 1);
          ((bf16*)Cp)[((long)(bb * NHD + (int)h) * SSD + s) * QKD + jj] = __float2bfloat16(v);
        }
      }
    }
  }
}

// ---------------- double-buffered counted-vmcnt GEMM (128x128, BK=64), f32 out ----------------
// A/B experiment (Wo only): flash-verified schedule -- stage(t+1) in flight across
// a raw s_barrier with vmcnt(8); 64KB LDS -> 2 blocks/CU. Pre-commit: revert if
// its dispatch is not faster than the single-buffer version.
__global__ __launch_bounds__(256)
void gemm_bt_db(const bf16* __restrict__ A, const bf16* __restrict__ Bm,
                const float* __restrict__ bias, float* __restrict__ Cp, int K, int ldc)
{
  int nwg = gridDim.x * gridDim.y;
  int lin = blockIdx.y * gridDim.x + blockIdx.x;
  int xcd = lin & 7, l8 = lin >> 3;
  int qd = nwg >> 3, rd = nwg & 7;
  int wg = (xcd < rd ? xcd * (qd + 1) : rd * (qd + 1) + (xcd - rd) * qd) + l8;
  int bx = wg % gridDim.x, by = wg / gridDim.x;
  int m0 = by * 128, n0 = bx * 128;

  __shared__ __align__(16) bf16 SA[2][8192];  // 2 x 16KB
  __shared__ __align__(16) bf16 SB[2][8192];

  const int tid  = threadIdx.x;
  const int lane = tid & 63;
  const int wv   = tid >> 6;
  const int wm   = (wv >> 1) << 6;
  const int wn   = (wv & 1) << 6;
  const int fr   = lane & 15;
  const int g4   = lane >> 4;

  int aoff[2][4], boff[2][4];
#pragma unroll
  for (int ks = 0; ks < 2; ++ks) {
#pragma unroll
    for (int t = 0; t < 4; ++t) {
      int ra = wm + t * 16 + fr;
      aoff[ks][t] = ra * 64 + (((ks * 4 + g4) ^ (ra & 7)) << 3);
      int rb = wn + t * 16 + fr;
      boff[ks][t] = rb * 64 + (((ks * 4 + g4) ^ (rb & 7)) << 3);
    }
  }

  floatx4 acc[4][4];
#pragma unroll
  for (int i = 0; i < 4; ++i)
#pragma unroll
    for (int j = 0; j < 4; ++j)
      acc[i][j] = (floatx4){0.f, 0.f, 0.f, 0.f};

  auto stage = [&](int t, int buf) {
    const long k0 = (long)t << 6;
#pragma unroll
    for (int it = 0; it < 4; ++it) {
      int seg = it * 256 + tid;
      int row = seg >> 3, cs = seg & 7;
      int scs = cs ^ (row & 7);
      GLD16(A  + (long)(m0 + row) * K + k0 + scs * 8, &SA[buf][(it * 256 + wv * 64) * 8]);
      GLD16(Bm + (long)(n0 + row) * K + k0 + scs * 8, &SB[buf][(it * 256 + wv * 64) * 8]);
    }
  };

  const int nt = K >> 6;
  stage(0, 0);

#pragma unroll 1
  for (int t = 0; t < nt; ++t) {
    if (t + 1 < nt) {
      stage(t + 1, (t + 1) & 1);
      asm volatile("s_waitcnt vmcnt(8)" ::: "memory");  // tile t's 8 loads landed
    } else {
      asm volatile("s_waitcnt vmcnt(0)" ::: "memory");
    }
    __builtin_amdgcn_sched_barrier(0);
    __builtin_amdgcn_s_barrier();
    __builtin_amdgcn_sched_barrier(0);

    const bf16* abuf = SA[t & 1];
    const bf16* bbuf = SB[t & 1];
#pragma unroll
    for (int ks = 0; ks < 2; ++ks) {
      short8 fa[4], fb[4];
#pragma unroll
      for (int tt = 0; tt < 4; ++tt) fa[tt] = *(const short8*)(abuf + aoff[ks][tt]);
#pragma unroll
      for (int tt = 0; tt < 4; ++tt) fb[tt] = *(const short8*)(bbuf + boff[ks][tt]);
      __builtin_amdgcn_s_setprio(1);
#pragma unroll
      for (int i = 0; i < 4; ++i)
#pragma unroll
        for (int j = 0; j < 4; ++j)
          acc[i][j] = __builtin_amdgcn_mfma_f32_16x16x32_bf16(fa[i], fb[j], acc[i][j], 0, 0, 0);
      __builtin_amdgcn_s_setprio(0);
    }

    __builtin_amdgcn_sched_barrier(0);
    __builtin_amdgcn_s_barrier();
    __builtin_amdgcn_sched_barrier(0);
  }

  int rq = g4 * 4;
#pragma unroll
  for (int i = 0; i < 4; ++i) {
#pragma unroll
    for (int j = 0; j < 4; ++j) {
      int col = n0 + wn + j * 16 + fr;
      float bv = bias ? bias[col] : 0.f;
#pragma unroll
      for (int r = 0; r < 4; ++r) {
        int rowg = m0 + wm + i * 16 + rq + r;
        Cp[(long)rowg * ldc + col] = acc[i][j][r] + bv;
      }
    }
  }
}

// ---------------- fused flash attention (causal), two tiles per block ----------------
// R4-verified loop. Q staged DENSE from head-major Qh (written by MODE-3 GEMM);
// rope+SCALEF applied in-register (R7-verified math); freqs prefetched as float4;
// stageKV(0) issued before rope so KV0 latency hides under the rope VALU.
__global__ __launch_bounds__(512, 2)
void flash_attn(const bf16* __restrict__ Qh, const bf16* __restrict__ Kh,
                const bf16* __restrict__ Vt, const float* __restrict__ freqs,
                bf16* __restrict__ attnall)
{
  const int lin = blockIdx.x;
  const int bh  = lin & 31;
  const int p   = lin >> 5;            // 0..7
  const int qtA = 15 - p;
  const int b = bh >> 4, h = bh & 15;

  const bf16* Qg = Qh + (long)bh * SSD * QKD;
  const bf16* Kg = Kh + (long)bh * SSD * QKD;
  const bf16* Vg = Vt + (long)bh * 128 * SSD;

  __shared__ __align__(16) bf16 SM[57344];
  bf16* KB0 = SM;
  bf16* KB1 = SM + 12288;
  bf16* VB0 = SM + 24576;
  bf16* VB1 = SM + 32768;
  bf16* PB  = SM + 40960;

  const int tid  = threadIdx.x;
  const int lane = tid & 63;
  const int wv   = tid >> 6;       // 0..7
  const int w4   = wv & 3;
  const int tb   = wv >> 2;        // 0 = tile A, 1 = tile B
  const int fr   = lane & 15;
  const int g4   = lane >> 4;

  const int qt    = tb ? (p) : (qtA);
  const int qbase = qt << 7;
  const int jmax  = 2 * qtA + 1;

  // --- prefetch rope freqs (2x float4 per row-block); drained by first barrier ---
  float4 fq4[2][2];
#pragma unroll
  for (int i = 0; i < 2; ++i) {
    int tok = qbase + w4 * 32 + i * 16 + fr;
    fq4[i][0] = *(const float4*)(freqs + (long)tok * 32 + g4 * 4);
    fq4[i][1] = *(const float4*)(freqs + (long)tok * 32 + 16 + g4 * 4);
  }

  long kofs[3]; int kdst[3];
#pragma unroll
  for (int it = 0; it < 3; ++it) {
    int seg = it * 512 + tid;
    int c = seg >> 8, rs = seg & 255;
    int r = rs >> 2, s = (rs & 3) ^ ((r >> 1) & 3);
    kofs[it] = (long)r * QKD + c * 32 + s * 8;
    kdst[it] = c * 2048 + rs * 8;
  }
  long vofs[2]; int vdst[2];
#pragma unroll
  for (int it = 0; it < 2; ++it) {
    int seg = it * 512 + tid;
    int c2 = seg >> 9, ds = seg & 511;
    int d = ds >> 2, s = (ds & 3) ^ ((d >> 1) & 3);
    vofs[it] = (long)d * SSD + c2 * 32 + s * 8;
    vdst[it] = c2 * 4096 + ds * 8;
  }
  int fsw[4];
#pragma unroll
  for (int n = 0; n < 4; ++n) {
    int row = n * 16 + fr;
    fsw[n] = row * 32 + (((g4 ^ (row >> 1)) & 3) << 3);
  }
  int vsw[8];
#pragma unroll
  for (int dn = 0; dn < 8; ++dn) {
    int row = dn * 16 + fr;
    vsw[dn] = row * 32 + (((g4 ^ (row >> 1)) & 3) << 3);
  }
  int qoff[2];
#pragma unroll
  for (int i = 0; i < 2; ++i) {
    int row = wv * 32 + i * 16 + fr;
    qoff[i] = row * 32 + (((g4 ^ (row >> 1)) & 3) << 3);
  }

  // --- stage both Q tiles (96KB) dense from Qh ---
  const int qbA = qtA << 7, qbB = p << 7;
#pragma unroll
  for (int it = 0; it < 12; ++it) {
    int seg = it * 512 + tid;
    int c = seg >> 10, rs = seg & 1023;
    int r = rs >> 2, s = (rs & 3) ^ ((r >> 1) & 3);
    int tok = (r < 128) ? (qbA + r) : (qbB + r - 128);
    GLD16(Qg + (long)tok * QKD + c * 32 + s * 8, SM + c * 8192 + rs * 8);
  }
  __syncthreads();  // Q visible; freqs in regs
  short8 qf[2][6];
#pragma unroll
  for (int i = 0; i < 2; ++i)
#pragma unroll
    for (int c = 0; c < 6; ++c)
      qf[i][c] = *(const short8*)(SM + c * 8192 + qoff[i]);

  __syncthreads();  // all qf reads done before K/V staging overwrites

  auto stageKV = [&](int jb2, bf16* kb2, bf16* vb2) {
#pragma unroll
    for (int it = 0; it < 3; ++it)
      GLD16(Kg + (long)jb2 * QKD + kofs[it], kb2 + kdst[it]);
#pragma unroll
    for (int it = 0; it < 2; ++it)
      GLD16(Vg + jb2 + vofs[it], vb2 + vdst[it]);
  };

  stageKV(0, KB0, VB0);   // KV0 latency hides under rope below

  // --- apply SCALEF (cols 0..127) and rope+SCALEF (cols 128..191) in-register ---
#pragma unroll
  for (int i = 0; i < 2; ++i) {
#pragma unroll
    for (int c = 0; c < 4; ++c) {
#pragma unroll
      for (int e = 0; e < 8; ++e) {
        bf16* el = (bf16*)&qf[i][c];
        el[e] = __float2bfloat16(__bfloat162float(el[e]) * SCALEF);
      }
    }
#pragma unroll
    for (int c = 4; c < 6; ++c) {
#pragma unroll
      for (int pp = 0; pp < 4; ++pp) {
        float f = (c == 4) ? ((const float*)&fq4[i][0])[pp] : ((const float*)&fq4[i][1])[pp];
        float cs, sn;
        __sincosf(f, &sn, &cs);
        bf16* el = (bf16*)&qf[i][c];
        float x0 = __bfloat162float(el[2 * pp]);
        float x1 = __bfloat162float(el[2 * pp + 1]);
        el[2 * pp]     = __float2bfloat16((x0 * cs - x1 * sn) * SCALEF);
        el[2 * pp + 1] = __float2bfloat16((x0 * sn + x1 * cs) * SCALEF);
      }
    }
  }

  floatx4 oacc[2][8];
#pragma unroll
  for (int i = 0; i < 2; ++i)
#pragma unroll
    for (int n = 0; n < 8; ++n) oacc[i][n] = (floatx4){0.f, 0.f, 0.f, 0.f};
  float mi[2][4], li[2][4];
#pragma unroll
  for (int i = 0; i < 2; ++i)
#pragma unroll
    for (int r = 0; r < 4; ++r) { mi[i][r] = -1e30f; li[i][r] = 0.f; }

#pragma unroll 1
  for (int j = 0; j <= jmax; ++j) {
    const int jb = j << 6;
    if (j < jmax) {
      stageKV((j + 1) << 6, (j & 1) ? KB0 : KB1, (j & 1) ? VB0 : VB1);
      asm volatile("s_waitcnt vmcnt(5)" ::: "memory");
    } else {
      asm volatile("s_waitcnt vmcnt(0)" ::: "memory");
    }
    __builtin_amdgcn_sched_barrier(0);
    __builtin_amdgcn_s_barrier();
    __builtin_amdgcn_sched_barrier(0);

    const bf16* kb = (j & 1) ? KB1 : KB0;
    const bf16* vb = (j & 1) ? VB1 : VB0;
    const bool active = (jb <= qbase + w4 * 32 + 31);
    if (active) {
      floatx4 sacc[2][4];
#pragma unroll
      for (int i = 0; i < 2; ++i)
#pragma unroll
        for (int n = 0; n < 4; ++n) sacc[i][n] = (floatx4){0.f, 0.f, 0.f, 0.f};
      __builtin_amdgcn_s_setprio(1);
#pragma unroll
      for (int c = 0; c < 6; ++c) {
#pragma unroll
        for (int n = 0; n < 4; ++n) {
          short8 fb = *(const short8*)(kb + c * 2048 + fsw[n]);
#pragma unroll
          for (int i = 0; i < 2; ++i)
            sacc[i][n] = __builtin_amdgcn_mfma_f32_16x16x32_bf16(qf[i][c], fb, sacc[i][n], 0, 0, 0);
        }
      }
      __builtin_amdgcn_s_setprio(0);

      float pm[2][4];
#pragma unroll
      for (int i = 0; i < 2; ++i) {
        const int rbase = qbase + w4 * 32 + i * 16;
        const bool diag = (jb + 63 > rbase);
#pragma unroll
        for (int r = 0; r < 4; ++r) {
          if (diag) {
            int rowg = rbase + g4 * 4 + r;
#pragma unroll
            for (int n = 0; n < 4; ++n)
              if ((jb + n * 16 + fr) > rowg) sacc[i][n][r] = -1e30f;
          }
          pm[i][r] = fmaxf(fmaxf(sacc[i][0][r], sacc[i][1][r]),
                           fmaxf(sacc[i][2][r], sacc[i][3][r]));
        }
      }
      int nn = 0;
#pragma unroll
      for (int i = 0; i < 2; ++i)
#pragma unroll
        for (int r = 0; r < 4; ++r) nn |= (pm[i][r] > mi[i][r]);
      if (__any(nn)) {
#pragma unroll
        for (int i = 0; i < 2; ++i) {
#pragma unroll
          for (int r = 0; r < 4; ++r) {
            float mx = pm[i][r];
#pragma unroll
            for (int off = 1; off < 16; off <<= 1) mx = fmaxf(mx, __shfl_xor(mx, off, 64));
            float mnew = fmaxf(mi[i][r], mx);
            float alpha = __expf(mi[i][r] - mnew);
            mi[i][r] = mnew;
            li[i][r] *= alpha;
#pragma unroll
            for (int n = 0; n < 8; ++n) oacc[i][n][r] *= alpha;
          }
        }
      }
#pragma unroll
      for (int i = 0; i < 2; ++i) {
#pragma unroll
        for (int r = 0; r < 4; ++r) {
          float acc = 0.f;
#pragma unroll
          for (int n = 0; n < 4; ++n) {
            float pv = __expf(sacc[i][n][r] - mi[i][r]);
            sacc[i][n][r] = pv;
            acc += pv;
          }
          li[i][r] += acc;
        }
      }

#pragma unroll
      for (int i = 0; i < 2; ++i) {
#pragma unroll
        for (int n = 0; n < 4; ++n) {
          int c2 = n >> 1;
          int col = (n & 1) * 16 + fr;
#pragma unroll
          for (int r = 0; r < 4; ++r) {
            int m = wv * 32 + i * 16 + g4 * 4 + r;
            int cw = (((col >> 3) ^ ((m >> 1) & 3)) << 3) | (col & 7);
            PB[c2 * 8192 + m * 32 + cw] = __float2bfloat16(sacc[i][n][r]);
          }
        }
      }

      __builtin_amdgcn_s_setprio(1);
#pragma unroll
      for (int c2 = 0; c2 < 2; ++c2) {
        short8 pf[2];
#pragma unroll
        for (int i = 0; i < 2; ++i)
          pf[i] = *(const short8*)(PB + c2 * 8192 + qoff[i]);
#pragma unroll
        for (int dn = 0; dn < 8; ++dn) {
          short8 vf = *(const short8*)(vb + c2 * 4096 + vsw[dn]);
#pragma unroll
          for (int i = 0; i < 2; ++i)
            oacc[i][dn] = __builtin_amdgcn_mfma_f32_16x16x32_bf16(pf[i], vf, oacc[i][dn], 0, 0, 0);
        }
      }
      __builtin_amdgcn_s_setprio(0);
    }

    __builtin_amdgcn_sched_barrier(0);
    __builtin_amdgcn_s_barrier();
    __builtin_amdgcn_sched_barrier(0);
  }

#pragma unroll
  for (int i = 0; i < 2; ++i) {
#pragma unroll
    for (int r = 0; r < 4; ++r) {
      float l = li[i][r];
#pragma unroll
      for (int off = 1; off < 16; off <<= 1) l += __shfl_xor(l, off, 64);
      float inv = 1.f / l;
      int m = qbase + w4 * 32 + i * 16 + g4 * 4 + r;
      bf16* orow = attnall + ((long)(b * SSD + m) * NHD + h) * 128;
#pragma unroll
      for (int dn = 0; dn < 8; ++dn)
        orow[dn * 16 + fr] = __float2bfloat16(oacc[i][dn][r] * inv);
    }
  }
}

// ---------------- fused fp32 -> bf16 converts (float4-vectorized) ----------------
// Wq_down and Wkv_down packed into ONE weight matrix Wd[2176][2048].
__device__ __forceinline__ void cvt4(const float* __restrict__ s, bf16* __restrict__ d,
                                     long se, long de) {
  float4 v = *(const float4*)(s + se);
  union { bf16 h[4]; uint2 u; } o;
  o.h[0] = __float2bfloat16(v.x); o.h[1] = __float2bfloat16(v.y);
  o.h[2] = __float2bfloat16(v.z); o.h[3] = __float2bfloat16(v.w);
  *(uint2*)(d + de) = o.u;
}

#define NX4   ((long)BSD * DIMD / 4)
#define NQD4  ((long)QLORA * DIMD / 4)
#define NKVD4 ((long)640 * DIMD / 4)
#define NQU4  ((long)3072 * QLORA / 4)
#define NKVU4 ((long)4096 * KVLORA / 4)
#define NWO4  ((long)DIMD * 2048 / 4)

__global__ __launch_bounds__(256)
void cvt_all(const float* __restrict__ x, const float* __restrict__ wqd,
             const float* __restrict__ wkvd, const float* __restrict__ wqu,
             const float* __restrict__ wkvu, const float* __restrict__ wo,
             bf16* __restrict__ dx, bf16* __restrict__ dwd, bf16* __restrict__ dwqu,
             bf16* __restrict__ dwkvu, bf16* __restrict__ dwo)
{
  long i = (long)blockIdx.x * 256 + threadIdx.x;
  if (i < NX4) { cvt4(x, dx, i * 4, i * 4); return; }
  i -= NX4;
  if (i < NQD4) { cvt4(wqd, dwd, i * 4, i * 4); return; }   // q rows of Wd
  i -= NQD4;
  if (i < NKVD4) {                                          // kv rows of Wd (offset 1536 rows)
    long e = i * 4;
    long r = e >> 11;             // kv-local row (cols = 2048)
    if (r < 576) cvt4(wkvd, dwd, e, (long)QLORA * DIMD + e);
    else *(uint2*)(dwd + (long)QLORA * DIMD + e) = (uint2){0u, 0u};
    return;
  }
  i -= NKVD4;
  if (i < NQU4) { cvt4(wqu, dwqu, i * 4, i * 4); return; }
  i -= NQU4;
  if (i < NKVU4) { cvt4(wkvu, dwkvu, i * 4, i * 4); return; }
  i -= NKVU4;
  if (i < NWO4) { cvt4(wo, dwo, i * 4, i * 4); return; }
}

// ---------------- rmsnorm (row per block), bf16 in (+opt fp32 bias), bf16 out ----------------
template<int L>
__global__ __launch_bounds__(256)
void rmsnorm_k(const bf16* __restrict__ in, const float* __restrict__ bias,
               const float* __restrict__ w, bf16* __restrict__ out, int ldin)
{
  constexpr int NIT = L / 256;
  long r = blockIdx.x;
  const bf16* row = in + r * ldin;
  int tid = threadIdx.x;
  float v[NIT];
  float ss = 0.f;
#pragma unroll
  for (int i = 0; i < NIT; ++i) {
    int c = tid + (i << 8);
    float x = __bfloat162float(row[c]) + (bias ? bias[c] : 0.f);
    v[i] = x;
    ss += x * x;
  }
  ss = block_sum(ss);
  float sc = rsqrtf(ss / (float)L + EPSF);
#pragma unroll
  for (int i = 0; i < NIT; ++i) {
    int c = tid + (i << 8);
    out[r * L + c] = __float2bfloat16(v[i] * sc * w[c]);
  }
}

// ---------------- build rope(K_rope) bcast -> Kh cols 128..191 (K_nope written by GEMM) ----------------
__global__ void build_k_rope(const bf16* __restrict__ kvkr, const float* __restrict__ kvb,
                             const float* __restrict__ freqs, bf16* __restrict__ Kh)
{
  int idx = blockIdx.x * 256 + threadIdx.x;
  if (idx >= BSD * NHD * 32) return;
  int i = idx & 31;
  int h = (idx >> 5) & 15;
  int srow = idx >> 9;
  int s = srow & (SSD - 1);
  int b = srow >> 11;
  float x0 = __bfloat162float(kvkr[(long)srow * NDOWN + 512 + 2 * i]) + kvb[512 + 2 * i];
  float x1 = __bfloat162float(kvkr[(long)srow * NDOWN + 513 + 2 * i]) + kvb[513 + 2 * i];
  float f = freqs[s * 32 + i];
  float c, sn;
  __sincosf(f, &sn, &c);
  bf16* dst = Kh + ((long)(b * NHD + h) * SSD + s) * QKD + 128 + 2 * i;
  dst[0] = __float2bfloat16(x0 * c - x1 * sn);
  dst[1] = __float2bfloat16(x0 * sn + x1 * c);
}

// ---------------- build V^T: kv(B,S,NH,256)[...,128:256] -> Vt (BH,128,S) bf16 ----------------
__global__ __launch_bounds__(256)
void build_vt(const bf16* __restrict__ kvf, bf16* __restrict__ Vt)
{
  __shared__ float t[32][33];
  int s0 = blockIdx.x * 32, d0 = blockIdx.y * 32, z = blockIdx.z;
  int b = z / NHD, h = z % NHD;
  int tx = threadIdx.x, ty = threadIdx.y;  // 32 x 8
#pragma unroll
  for (int r = 0; r < 4; ++r) {
    int sl = ty + r * 8;
    t[sl][tx] = __bfloat162float(kvf[(long)(b * SSD + s0 + sl) * 4096 + h * 256 + 128 + d0 + tx]);
  }
  __syncthreads();
#pragma unroll
  for (int r = 0; r < 4; ++r) {
    int dl = ty + r * 8;
    Vt[((long)z * 128 + d0 + dl) * SSD + s0 + tx] = __float2bfloat16(t[tx][dl]);
  }
}

// ---------------- diagnostic: ws too small ----------------
__global__ void diag_fill(float* out) { out[blockIdx.x * 256 + threadIdx.x] = 1000.0f; }

extern "C" void kernel_launch(void* const* d_in, const int* in_sizes, int n_in,
                              void* d_out, int out_size, void* d_ws, size_t ws_size,
                              hipStream_t stream)
{
  const float* x     = (const float*)d_in[0];
  const float* freqs = (const float*)d_in[1];
  const float* Wqd   = (const float*)d_in[3];
  const float* Wqdb  = (const float*)d_in[4];
  const float* qnw   = (const float*)d_in[5];
  const float* Wqu   = (const float*)d_in[6];
  const float* Wqub  = (const float*)d_in[7];
  const float* Wkvd  = (const float*)d_in[8];
  const float* Wkvdb = (const float*)d_in[9];
  const float* kvnw  = (const float*)d_in[10];
  const float* Wkvu  = (const float*)d_in[11];
  const float* Wkvub = (const float*)d_in[12];
  const float* Wo    = (const float*)d_in[13];
  const float* Wob   = (const float*)d_in[14];
  float* out = (float*)d_out;

  char* ws = (char*)d_ws;
  size_t off = 0;
  auto alloc = [&](size_t bytes) {
    void* p = ws + off;
    off += (bytes + 255) & ~(size_t)255;
    return p;
  };

  bf16* Wd16   = (bf16*)alloc((size_t)NDOWN * DIMD * 2);   // fused down weights
  bf16* Wqu16  = (bf16*)alloc((size_t)3072 * QLORA * 2);
  bf16* Wkvu16 = (bf16*)alloc((size_t)4096 * KVLORA * 2);
  bf16* Wo16   = (bf16*)alloc((size_t)DIMD * 2048 * 2);
  bf16* x16    = (bf16*)alloc((size_t)BSD * DIMD * 2);
  bf16* Ra     = (bf16*)alloc((size_t)BSD * NDOWN * 2);    // fused down output (qdown | kvkr)
  bf16* Rb     = (bf16*)alloc((size_t)BSD * QLORA * 2);    // qlat, then kvlat
  bf16* Rc     = (bf16*)alloc((size_t)BSD * 4096 * 2);     // kvf, then attnall
  bf16* Qh16   = (bf16*)alloc((size_t)BHN * SSD * QKD * 2);
  bf16* Kh16   = (bf16*)alloc((size_t)BHN * SSD * QKD * 2);
  bf16* Vt16   = (bf16*)alloc((size_t)BHN * 128 * SSD * 2);

  bf16* qdown   = Ra;                  // cols 0..1535 of Ra (stride NDOWN)
  bf16* kvkr    = Ra + QLORA;          // cols 1536..2175 of Ra (stride NDOWN)
  bf16* qlat16  = Rb;  bf16* kvlat16 = Rb;
  bf16* kvf     = Rc;  bf16* attnall = Rc;

  if (off > ws_size) { diag_fill<<<8, 256, 0, stream>>>(out); return; }

  dim3 blk(256);
  auto cdiv = [](long a, long b) { return (int)((a + b - 1) / b); };

  // --- all fp32->bf16 converts in one dispatch ---
  long tot4 = NX4 + NQD4 + NKVD4 + NQU4 + NKVU4 + NWO4;
  cvt_all<<<cdiv(tot4, 256), blk, 0, stream>>>(x, Wqd, Wkvd, Wqu, Wkvu, Wo,
                                               x16, Wd16, Wqu16, Wkvu16, Wo16);

  // --- fused down-projection: [qdown | kvkr] = x * Wd^T (bias folded into rmsnorm) ---
  gemm_bt<1><<<dim3(NDOWN / 128, BSD / 128), blk, 0, stream>>>(
      x16, Wd16, nullptr, Ra, DIMD, NDOWN, nullptr);

  // --- Q path: up-proj writes head-major Qh directly (MODE 3); rope in flash ---
  rmsnorm_k<QLORA><<<BSD, blk, 0, stream>>>(qdown, Wqdb, qnw, qlat16, NDOWN);
  gemm_bt<3><<<dim3(3072 / 128, BSD / 128), blk, 0, stream>>>(
      qlat16, Wqu16, Wqub, Qh16, QLORA, 3072, nullptr);

  // --- KV path: up-proj writes K_nope direct to Kh (MODE 2), V to kvf ---
  rmsnorm_k<KVLORA><<<BSD, blk, 0, stream>>>(kvkr, Wkvdb, kvnw, kvlat16, NDOWN);
  gemm_bt<2><<<dim3(4096 / 128, BSD / 128), blk, 0, stream>>>(
      kvlat16, Wkvu16, Wkvub, kvf, KVLORA, 4096, Kh16);
  build_k_rope<<<cdiv((long)BSD * NHD * 32, 256), blk, 0, stream>>>(kvkr, Wkvdb, freqs, Kh16);
  build_vt<<<dim3(SSD / 32, 128 / 32, BHN), dim3(32, 8), 0, stream>>>(kvf, Vt16);

  // --- fused flash attention: 256 two-tile blocks (1/CU), 8 waves each ---
  flash_attn<<<dim3(256), dim3(512), 0, stream>>>(Qh16, Kh16, Vt16, freqs, attnall);

  // --- output projection (fp32 out), double-buffered counted-vmcnt A/B ---
  gemm_bt_db<<<dim3(2048 / 128, BSD / 128), blk, 0, stream>>>(
      attnall, Wo16, Wob, out, 2048, DIMD);
}